// Round 1
// baseline (2659.995 us; speedup 1.0000x reference)
//
#include <hip/hip_runtime.h>
#include <hip/hip_bf16.h>
#include <cfloat>

#define B_ 4
#define N_ 2048
#define NG_ 12
#define K_ 16
#define H_ 64
#define C_ 128
#define BD_ 64
#define M_ 512

__device__ __forceinline__ float gelu_f(float x){
  float x3 = x*x*x;
  return 0.5f*x*(1.0f + tanhf(0.7978845608028654f*(x + 0.044715f*x3)));
}

// ---------------- K1: lift + embed -> x1 [B,N,NG,H] ----------------
__global__ __launch_bounds__(256) void k_lift(
    const float* __restrict__ pos, const float* __restrict__ normal,
    const float* __restrict__ grid,
    const float* __restrict__ e1w, const float* __restrict__ e1b,
    const float* __restrict__ e2w, const float* __restrict__ e2b,
    float* __restrict__ x1){
  int tid = threadIdx.x;
  int q = tid>>6, lane = tid&63;
  int fid = blockIdx.x*4 + q;
  int g = fid % NG_;
  int n = (fid / NG_) % N_;
  int b = fid / (NG_*N_);
  const float* nm = normal + (size_t)(b*N_+n)*3;
  const float* pp = pos + (size_t)(b*N_+n)*3;
  const float* gg = grid + g*3;
  float f0 = nm[0]*gg[0] + nm[1]*gg[1] + nm[2]*gg[2];
  float t = e1b[lane] + f0*e1w[lane] + pp[0]*e1w[64+lane] + pp[1]*e1w[128+lane] + pp[2]*e1w[192+lane];
  __shared__ float ts[4][64];
  ts[q][lane] = gelu_f(t);
  __syncthreads();
  float acc = e2b[lane];
  #pragma unroll
  for (int i=0;i<64;++i) acc = fmaf(ts[q][i], e2w[i*64+lane], acc);
  x1[(size_t)fid*64 + lane] = acc;
}

// ---------------- K2: farthest point sampling -> ps [B,M,3] ----------------
__global__ __launch_bounds__(256) void k_fps(const float* __restrict__ pos, float* __restrict__ ps){
  int b = blockIdx.x, tid = threadIdx.x;
  __shared__ float posS[N_*3];
  for (int i=tid;i<N_*3;i+=256) posS[i] = pos[(size_t)b*N_*3 + i];
  __syncthreads();
  float px[8],py[8],pz[8],d[8];
  #pragma unroll
  for (int j=0;j<8;++j){
    int n = tid + 256*j;
    px[j]=posS[n*3]; py[j]=posS[n*3+1]; pz[j]=posS[n*3+2];
    d[j]=1e10f;
  }
  __shared__ float wv[4]; __shared__ int wi[4]; __shared__ int bc;
  int wave = tid>>6, lane = tid&63;
  int last = 0;
  for (int s=0;s<M_;++s){
    float lx=posS[last*3], ly=posS[last*3+1], lz=posS[last*3+2];
    if (tid==0){ float* o = ps + ((size_t)b*M_+s)*3; o[0]=lx;o[1]=ly;o[2]=lz; }
    #pragma unroll
    for (int j=0;j<8;++j){
      float dx=__fsub_rn(px[j],lx), dy=__fsub_rn(py[j],ly), dz=__fsub_rn(pz[j],lz);
      float dist=__fadd_rn(__fadd_rn(__fmul_rn(dx,dx),__fmul_rn(dy,dy)),__fmul_rn(dz,dz));
      d[j]=fminf(d[j],dist);
    }
    if (s==M_-1) break;
    float v=-1.0f; int vi=0x7fffffff;
    #pragma unroll
    for (int j=0;j<8;++j){ if (d[j]>v){ v=d[j]; vi=tid+256*j; } }
    #pragma unroll
    for (int off=32; off>0; off>>=1){
      float ov=__shfl_xor(v,off); int oi=__shfl_xor(vi,off);
      if (ov>v || (ov==v && oi<vi)){ v=ov; vi=oi; }
    }
    if (lane==0){ wv[wave]=v; wi[wave]=vi; }
    __syncthreads();
    if (tid==0){
      float bv=wv[0]; int bi=wi[0];
      for (int w=1;w<4;++w){ if (wv[w]>bv || (wv[w]==bv && wi[w]<bi)){ bv=wv[w]; bi=wi[w]; } }
      bc=bi;
    }
    __syncthreads();
    last=bc;
  }
}

// ---------------- K3: exact KNN (k smallest d2, stable ties) ----------------
template<int NP>
__global__ __launch_bounds__(64) void k_knn(const float* __restrict__ qp, const float* __restrict__ pool,
                                            int* __restrict__ out){
  constexpr int R = NP/64;
  int lane = threadIdx.x;
  int qm = blockIdx.x;            // b*M + m
  int b = qm / M_;
  const float* q = qp + (size_t)qm*3;
  float qx=q[0], qy=q[1], qz=q[2];
  float d2[R];
  #pragma unroll
  for (int j=0;j<R;++j){
    int n = lane + 64*j;
    const float* p = pool + ((size_t)b*NP + n)*3;
    float dx=__fsub_rn(qx,p[0]), dy=__fsub_rn(qy,p[1]), dz=__fsub_rn(qz,p[2]);
    d2[j]=__fadd_rn(__fadd_rn(__fmul_rn(dx,dx),__fmul_rn(dy,dy)),__fmul_rn(dz,dz));
  }
  for (int r=0;r<K_;++r){
    float v=FLT_MAX; int vi=0x7fffffff;
    #pragma unroll
    for (int j=0;j<R;++j){ if (d2[j]<v){ v=d2[j]; vi=lane+64*j; } }
    #pragma unroll
    for (int off=32; off>0; off>>=1){
      float ov=__shfl_xor(v,off); int oi=__shfl_xor(vi,off);
      if (ov<v || (ov==v && oi<vi)){ v=ov; vi=oi; }
    }
    if (lane==0) out[(size_t)qm*K_ + r] = vi;
    #pragma unroll
    for (int j=0;j<R;++j){ if (vi == lane + 64*j) d2[j] = FLT_MAX; }
  }
}

// ---------------- K4: fused down-proj + relu + neighbor-max -> xA [B,M,NG,C] ----------------
__global__ __launch_bounds__(256) void k_downmax(
    const float* __restrict__ x1, const int* __restrict__ nbrD,
    const float* __restrict__ dw, const float* __restrict__ db,
    float* __restrict__ xA){
  int bm = blockIdx.x; int b = bm / M_;
  int tid = threadIdx.x;
  __shared__ int nb[K_];
  __shared__ float xs[K_][NG_*H_];     // 48 KB
  if (tid<K_) nb[tid] = nbrD[(size_t)bm*K_ + tid];
  __syncthreads();
  for (int idx=tid; idx<K_*NG_*H_; idx+=256){
    int k = idx / (NG_*H_), r = idx % (NG_*H_);
    xs[k][r] = x1[((size_t)(b*N_) + nb[k])*(NG_*H_) + r];
  }
  __syncthreads();
  int c = tid & 127, gh = tid >> 7;
  float dbc = db[c];
  for (int gi=0; gi<6; ++gi){
    int g = gh*6 + gi;
    float acc[K_];
    #pragma unroll
    for (int k=0;k<K_;++k) acc[k]=dbc;
    for (int i4=0;i4<16;++i4){
      float w0 = dw[(i4*4+0)*C_ + c];
      float w1 = dw[(i4*4+1)*C_ + c];
      float w2 = dw[(i4*4+2)*C_ + c];
      float w3 = dw[(i4*4+3)*C_ + c];
      #pragma unroll
      for (int k=0;k<K_;++k){
        float4 xv = *(const float4*)&xs[k][g*H_ + i4*4];
        acc[k] = fmaf(xv.x,w0,fmaf(xv.y,w1,fmaf(xv.z,w2,fmaf(xv.w,w3,acc[k]))));
      }
    }
    float best = acc[0];
    #pragma unroll
    for (int k=1;k<K_;++k) best = fmaxf(best, acc[k]);
    xA[(size_t)bm*(NG_*C_) + g*C_ + c] = fmaxf(best, 0.0f);
  }
}

// ---------------- K5: kbR basis MLP [NG,NG,BD] ----------------
__global__ __launch_bounds__(128) void k_kbR(
    const float* __restrict__ grid, const float* __restrict__ rff,
    const float* __restrict__ w1, const float* __restrict__ b1,
    const float* __restrict__ w2, const float* __restrict__ b2,
    float* __restrict__ kbR){
  int gm = blockIdx.x / NG_, gn = blockIdx.x % NG_;
  int j = threadIdx.x;
  float z = grid[gm*3]*grid[gn*3] + grid[gm*3+1]*grid[gn*3+1] + grid[gm*3+2]*grid[gn*3+2];
  __shared__ float fs[128], hs[128];
  int jj = j & 63;
  float ang = 6.283185307179586f * (z * rff[jj]);
  fs[j] = (j<64) ? sinf(ang) : cosf(ang);
  __syncthreads();
  float acc = b1[j];
  for (int i=0;i<128;++i) acc = fmaf(fs[i], w1[i*128+j], acc);
  hs[j] = gelu_f(acc);
  __syncthreads();
  if (j < 64){
    float a2 = b2[j];
    for (int i=0;i<128;++i) a2 = fmaf(hs[i], w2[i*64+j], a2);
    kbR[(size_t)blockIdx.x*64 + j] = gelu_f(a2);
  }
}

// ---------------- K6: kR = kbR @ kR_w + b  [NG,NG,C] ----------------
__global__ __launch_bounds__(128) void k_kR(
    const float* __restrict__ kbR, const float* __restrict__ kRw, const float* __restrict__ kRb,
    float* __restrict__ kR){
  int pair = blockIdx.x; int c = threadIdx.x;
  __shared__ float kb[64];
  if (c<64) kb[c] = kbR[(size_t)pair*64 + c];
  __syncthreads();
  float acc = kRb[c];
  for (int d=0;d<64;++d) acc = fmaf(kb[d], kRw[d*128+c], acc);
  kR[(size_t)pair*128 + c] = acc;
}

// ---------------- K7: kbx basis MLP (big GEMM) -> [B*M*K*NG, BD] ----------------
__global__ __launch_bounds__(256) void k_kbx(
    const float* __restrict__ ps, const int* __restrict__ nbr,
    const float* __restrict__ grid, const float* __restrict__ rff,
    const float* __restrict__ w1, const float* __restrict__ b1,
    const float* __restrict__ w2, const float* __restrict__ b2,
    float* __restrict__ kbx){
  int tid = threadIdx.x;
  __shared__ float z0s[32], z1s[32];
  __shared__ float rw[128];
  __shared__ float Ft[128][32];       // 16 KB  (f-dim major, fiber minor)
  __shared__ float WcF[4096];         // 16 KB weight chunk
  __shared__ float Hs[32][129];       // 16.5 KB padded
  if (tid<128) rw[tid] = rff[tid];
  if (tid<32){
    int fid = blockIdx.x*32 + tid;
    int g = fid % NG_;
    int k = (fid/NG_) % K_;
    int bm = fid / (NG_*K_);          // b*M+m
    int b = bm / M_;
    int nb = nbr[(size_t)bm*K_ + k];
    const float* pm = ps + (size_t)bm*3;
    const float* pn = ps + ((size_t)(b*M_) + nb)*3;
    float rx = pn[0]-pm[0], ry = pn[1]-pm[1], rz3 = pn[2]-pm[2];
    const float* gg = grid + g*3;
    float rz = rx*gg[0] + ry*gg[1] + rz3*gg[2];
    float vx = rx - rz*gg[0], vy = ry - rz*gg[1], vz = rz3 - rz*gg[2];
    float rxy = sqrtf(vx*vx + vy*vy + vz*vz + 1e-12f);
    z0s[tid]=rxy; z1s[tid]=rz;
  }
  __syncthreads();
  { // Phase A: fill F (RFF features), transposed
    int f = tid & 31;
    int kb0 = (tid>>5)*16;
    float z0=z0s[f], z1=z1s[f];
    #pragma unroll
    for (int qq=0;qq<16;++qq){
      int kd = kb0+qq; int jj = kd & 63;
      float ang = 6.283185307179586f * (z0*rw[jj] + z1*rw[64+jj]);
      Ft[kd][f] = (kd<64) ? sinf(ang) : cosf(ang);
    }
  }
  // Phase B: H = gelu(F @ W1 + b1)
  int o = tid>>4, fg = tid&15;
  int j0 = o*8, f0 = fg*2;
  float acc[2][8];
  #pragma unroll
  for (int d=0; d<2; ++d)
    #pragma unroll
    for (int e=0;e<8;++e) acc[d][e]=0.f;
  const float4* w1v = (const float4*)w1;
  for (int kc=0;kc<4;++kc){
    __syncthreads();
    #pragma unroll
    for (int qq=0;qq<4;++qq){
      int slot = tid + qq*256;
      ((float4*)WcF)[slot] = w1v[kc*1024 + slot];
    }
    __syncthreads();
    #pragma unroll
    for (int kk=0;kk<32;++kk){
      float2 fv = *(const float2*)&Ft[kc*32+kk][f0];
      float w8[8];
      *(float4*)&w8[0] = *(const float4*)&WcF[kk*128 + j0];
      *(float4*)&w8[4] = *(const float4*)&WcF[kk*128 + j0 + 4];
      #pragma unroll
      for (int e=0;e<8;++e){
        acc[0][e] = fmaf(fv.x, w8[e], acc[0][e]);
        acc[1][e] = fmaf(fv.y, w8[e], acc[1][e]);
      }
    }
  }
  #pragma unroll
  for (int d=0;d<2;++d)
    #pragma unroll
    for (int e=0;e<8;++e)
      Hs[f0+d][j0+e] = gelu_f(b1[j0+e] + acc[d][e]);
  // Phase C: out = gelu(H @ W2 + b2)
  int f = tid & 31, co = tid>>5;
  int jc = co*8;
  float a2[8];
  #pragma unroll
  for (int e=0;e<8;++e) a2[e]=0.f;
  const float4* w2v = (const float4*)w2;
  for (int kc=0;kc<4;++kc){
    __syncthreads();
    #pragma unroll
    for (int qq=0;qq<2;++qq){
      int slot = tid + qq*256;
      ((float4*)WcF)[slot] = w2v[kc*512 + slot];
    }
    __syncthreads();
    #pragma unroll
    for (int kk=0;kk<32;++kk){
      float h = Hs[f][kc*32+kk];
      float w8[8];
      *(float4*)&w8[0] = *(const float4*)&WcF[kk*64 + jc];
      *(float4*)&w8[4] = *(const float4*)&WcF[kk*64 + jc + 4];
      #pragma unroll
      for (int e=0;e<8;++e) a2[e] = fmaf(h, w8[e], a2[e]);
    }
  }
  size_t fido = (size_t)blockIdx.x*32 + f;
  float o8[8];
  #pragma unroll
  for (int e=0;e<8;++e) o8[e] = gelu_f(b2[jc+e] + a2[e]);
  *(float4*)&kbx[fido*64 + jc]     = *(const float4*)&o8[0];
  *(float4*)&kbx[fido*64 + jc + 4] = *(const float4*)&o8[4];
}

// ---------------- K8: interaction layer ----------------
__global__ __launch_bounds__(256) void k_inter(
    const float* __restrict__ xin, const int* __restrict__ nbr,
    const float* __restrict__ kbx, const float* __restrict__ kR,
    const float* __restrict__ kxw, const float* __restrict__ kxb,
    const float* __restrict__ mw, const float* __restrict__ mb,
    float* __restrict__ xout){
  int bm = blockIdx.x; int b = bm / M_;
  int tid = threadIdx.x;
  int c = tid & 127, gh = tid >> 7;
  __shared__ float kbs[NG_*BD_];    // 3 KB
  __shared__ float xns[NG_*C_];     // 6 KB
  __shared__ float aggS[NG_][C_];   // 6 KB
  __shared__ float yS[NG_][C_];     // 6 KB
  float accg[6] = {0,0,0,0,0,0};
  float kxbc = kxb[c];
  for (int k=0;k<K_;++k){
    int nb = nbr[(size_t)bm*K_ + k];
    __syncthreads();
    for (int idx=tid; idx<NG_*BD_; idx+=256)
      kbs[idx] = kbx[((size_t)bm*K_ + k)*(NG_*BD_) + idx];
    for (int idx=tid; idx<NG_*C_; idx+=256)
      xns[idx] = xin[((size_t)(b*M_) + nb)*(NG_*C_) + idx];
    __syncthreads();
    float t6[6] = {0,0,0,0,0,0};
    for (int d4=0; d4<16; ++d4){
      float w0 = kxw[(d4*4+0)*C_+c], w1 = kxw[(d4*4+1)*C_+c],
            w2 = kxw[(d4*4+2)*C_+c], w3 = kxw[(d4*4+3)*C_+c];
      #pragma unroll
      for (int gi=0; gi<6; ++gi){
        int g = gh*6+gi;
        float4 kv = *(const float4*)&kbs[g*BD_ + d4*4];
        t6[gi] = fmaf(kv.x,w0,fmaf(kv.y,w1,fmaf(kv.z,w2,fmaf(kv.w,w3,t6[gi]))));
      }
    }
    #pragma unroll
    for (int gi=0; gi<6; ++gi){
      int g = gh*6+gi;
      accg[gi] = fmaf(t6[gi]+kxbc, xns[g*C_+c], accg[gi]);
    }
  }
  __syncthreads();
  #pragma unroll
  for (int gi=0; gi<6; ++gi)
    aggS[gh*6+gi][c] = accg[gi] * (1.0f/16.0f);
  __syncthreads();
  #pragma unroll
  for (int gi=0; gi<6; ++gi){
    int g = gh*6+gi;
    float yv = 0.f;
    #pragma unroll
    for (int n=0;n<NG_;++n) yv = fmaf(aggS[n][c], kR[((size_t)g*NG_+n)*C_ + c], yv);
    yS[g][c] = yv * (1.0f/12.0f);
  }
  __syncthreads();
  float m6[6] = {0,0,0,0,0,0};
  for (int i4=0;i4<32;++i4){
    float w0 = mw[(i4*4+0)*C_+c], w1 = mw[(i4*4+1)*C_+c],
          w2 = mw[(i4*4+2)*C_+c], w3 = mw[(i4*4+3)*C_+c];
    #pragma unroll
    for (int gi=0;gi<6;++gi){
      int g = gh*6+gi;
      float4 yv = *(const float4*)&yS[g][i4*4];
      m6[gi] = fmaf(yv.x,w0,fmaf(yv.y,w1,fmaf(yv.z,w2,fmaf(yv.w,w3,m6[gi]))));
    }
  }
  float mbc = mb[c];
  #pragma unroll
  for (int gi=0;gi<6;++gi){
    int g = gh*6+gi;
    size_t off = (size_t)bm*(NG_*C_) + g*C_ + c;
    xout[off] = xin[off] + gelu_f(m6[gi] + mbc);
  }
}

// ---------------- K9: readout ----------------
__global__ __launch_bounds__(256) void k_readout(
    const float* __restrict__ x,
    const float* __restrict__ p1w, const float* __restrict__ p1b,
    const float* __restrict__ p2w, const float* __restrict__ p2b,
    const float* __restrict__ p3w, const float* __restrict__ p3b,
    float* __restrict__ out){
  int b = blockIdx.x, tid = threadIdx.x;
  int c = tid & 127, half = tid >> 7;
  __shared__ float red[256];
  float acc = 0.f;
  const float* xb = x + (size_t)b*M_*NG_*C_;
  for (int r = half; r < M_*NG_; r += 2)
    acc += xb[(size_t)r*C_ + c];
  red[tid] = acc;
  __syncthreads();
  __shared__ float gs[128];
  if (half==0) gs[c] = (red[c] + red[128+c]) * (1.0f/(M_*NG_));
  __syncthreads();
  __shared__ float h1[256];
  {
    float a = p1b[tid];
    for (int i=0;i<128;++i) a = fmaf(gs[i], p1w[i*256+tid], a);
    h1[tid] = gelu_f(a);
  }
  __syncthreads();
  __shared__ float h2[64];
  if (tid<64){
    float a = p2b[tid];
    for (int i=0;i<256;++i) a = fmaf(h1[i], p2w[i*64+tid], a);
    h2[tid] = gelu_f(a);
  }
  __syncthreads();
  if (tid==0){
    float a = p3b[0];
    for (int i=0;i<64;++i) a = fmaf(h2[i], p3w[i], a);
    out[b] = a;
  }
}

extern "C" void kernel_launch(void* const* d_in, const int* in_sizes, int n_in,
                              void* d_out, int out_size, void* d_ws, size_t ws_size,
                              hipStream_t stream){
  const float* pos    = (const float*)d_in[0];
  const float* normal = (const float*)d_in[1];
  const float* grid   = (const float*)d_in[2];
  const float* e1w = (const float*)d_in[3];  const float* e1b = (const float*)d_in[4];
  const float* e2w = (const float*)d_in[5];  const float* e2b = (const float*)d_in[6];
  const float* dww = (const float*)d_in[7];  const float* dwb = (const float*)d_in[8];
  const float* bx_rff = (const float*)d_in[9];
  const float* bx1w = (const float*)d_in[10]; const float* bx1b = (const float*)d_in[11];
  const float* bx2w = (const float*)d_in[12]; const float* bx2b = (const float*)d_in[13];
  const float* bR_rff = (const float*)d_in[14];
  const float* bR1w = (const float*)d_in[15]; const float* bR1b = (const float*)d_in[16];
  const float* bR2w = (const float*)d_in[17]; const float* bR2b = (const float*)d_in[18];
  const float* i1kxw = (const float*)d_in[19]; const float* i1kxb = (const float*)d_in[20];
  const float* i1kRw = (const float*)d_in[21]; const float* i1kRb = (const float*)d_in[22];
  const float* i1mw  = (const float*)d_in[23]; const float* i1mb  = (const float*)d_in[24];
  const float* i2kxw = (const float*)d_in[25]; const float* i2kxb = (const float*)d_in[26];
  const float* i2kRw = (const float*)d_in[27]; const float* i2kRb = (const float*)d_in[28];
  const float* i2mw  = (const float*)d_in[29]; const float* i2mb  = (const float*)d_in[30];
  const float* p1w = (const float*)d_in[31]; const float* p1b = (const float*)d_in[32];
  const float* p2w = (const float*)d_in[33]; const float* p2b = (const float*)d_in[34];
  const float* p3w = (const float*)d_in[35]; const float* p3b = (const float*)d_in[36];
  float* out = (float*)d_out;

  float* ws = (float*)d_ws;
  size_t o = 0;
  float* x1  = ws + o; o += (size_t)B_*N_*NG_*H_;       // 6,291,456
  float* psb = ws + o; o += (size_t)B_*M_*3;            // 6,144
  float* xA  = ws + o; o += (size_t)B_*M_*NG_*C_;       // 3,145,728
  float* xB  = ws + o; o += (size_t)B_*M_*NG_*C_;       // 3,145,728
  float* kbx = ws + o; o += (size_t)B_*M_*K_*NG_*BD_;   // 25,165,824
  float* kbR = ws + o; o += (size_t)NG_*NG_*BD_;        // 9,216
  float* kRb = ws + o; o += (size_t)NG_*NG_*C_;         // 18,432
  int* nbrD  = (int*)(ws + o); o += (size_t)B_*M_*K_;   // 32,768
  int* nbrS  = (int*)(ws + o); o += (size_t)B_*M_*K_;   // 32,768

  k_lift<<<B_*N_*NG_/4, 256, 0, stream>>>(pos, normal, grid, e1w,e1b,e2w,e2b, x1);
  k_fps<<<B_, 256, 0, stream>>>(pos, psb);
  k_knn<N_><<<B_*M_, 64, 0, stream>>>(psb, pos, nbrD);
  k_knn<M_><<<B_*M_, 64, 0, stream>>>(psb, psb, nbrS);
  k_downmax<<<B_*M_, 256, 0, stream>>>(x1, nbrD, dww, dwb, xA);
  k_kbR<<<NG_*NG_, 128, 0, stream>>>(grid, bR_rff, bR1w, bR1b, bR2w, bR2b, kbR);
  k_kbx<<<(B_*M_*K_*NG_)/32, 256, 0, stream>>>(psb, nbrS, grid, bx_rff, bx1w, bx1b, bx2w, bx2b, kbx);
  k_kR<<<NG_*NG_, 128, 0, stream>>>(kbR, i1kRw, i1kRb, kRb);
  k_inter<<<B_*M_, 256, 0, stream>>>(xA, nbrS, kbx, kRb, i1kxw, i1kxb, i1mw, i1mb, xB);
  k_kR<<<NG_*NG_, 128, 0, stream>>>(kbR, i2kRw, i2kRb, kRb);
  k_inter<<<B_*M_, 256, 0, stream>>>(xB, nbrS, kbx, kRb, i2kxw, i2kxb, i2mw, i2mb, xA);
  k_readout<<<B_, 256, 0, stream>>>(xA, p1w,p1b,p2w,p2b,p3w,p3b, out);
}

// Round 2
// 1939.100 us; speedup vs baseline: 1.3718x; 1.3718x over previous
//
#include <hip/hip_runtime.h>
#include <hip/hip_bf16.h>
#include <cfloat>

#define B_ 4
#define N_ 2048
#define NG_ 12
#define K_ 16
#define H_ 64
#define C_ 128
#define BD_ 64
#define M_ 512

__device__ __forceinline__ float gelu_f(float x){
  float x3 = x*x*x;
  return 0.5f*x*(1.0f + tanhf(0.7978845608028654f*(x + 0.044715f*x3)));
}

// ---------------- K1: lift + embed -> x1 [B,N,NG,H] ----------------
__global__ __launch_bounds__(256) void k_lift(
    const float* __restrict__ pos, const float* __restrict__ normal,
    const float* __restrict__ grid,
    const float* __restrict__ e1w, const float* __restrict__ e1b,
    const float* __restrict__ e2w, const float* __restrict__ e2b,
    float* __restrict__ x1){
  int tid = threadIdx.x;
  int q = tid>>6, lane = tid&63;
  int fid = blockIdx.x*4 + q;
  int g = fid % NG_;
  int n = (fid / NG_) % N_;
  int b = fid / (NG_*N_);
  const float* nm = normal + (size_t)(b*N_+n)*3;
  const float* pp = pos + (size_t)(b*N_+n)*3;
  const float* gg = grid + g*3;
  float f0 = nm[0]*gg[0] + nm[1]*gg[1] + nm[2]*gg[2];
  float t = e1b[lane] + f0*e1w[lane] + pp[0]*e1w[64+lane] + pp[1]*e1w[128+lane] + pp[2]*e1w[192+lane];
  __shared__ float ts[4][64];
  ts[q][lane] = gelu_f(t);
  __syncthreads();
  float acc = e2b[lane];
  #pragma unroll
  for (int i=0;i<64;++i) acc = fmaf(ts[q][i], e2w[i*64+lane], acc);
  x1[(size_t)fid*64 + lane] = acc;
}

// ---------------- K2: farthest point sampling -> ps [B,M,3] ----------------
__global__ __launch_bounds__(256) void k_fps(const float* __restrict__ pos, float* __restrict__ ps){
  int b = blockIdx.x, tid = threadIdx.x;
  __shared__ float posS[N_*3];
  for (int i=tid;i<N_*3;i+=256) posS[i] = pos[(size_t)b*N_*3 + i];
  __syncthreads();
  float px[8],py[8],pz[8],d[8];
  #pragma unroll
  for (int j=0;j<8;++j){
    int n = tid + 256*j;
    px[j]=posS[n*3]; py[j]=posS[n*3+1]; pz[j]=posS[n*3+2];
    d[j]=1e10f;
  }
  __shared__ float wv[4]; __shared__ int wi[4]; __shared__ int bc;
  int wave = tid>>6, lane = tid&63;
  int last = 0;
  for (int s=0;s<M_;++s){
    float lx=posS[last*3], ly=posS[last*3+1], lz=posS[last*3+2];
    if (tid==0){ float* o = ps + ((size_t)b*M_+s)*3; o[0]=lx;o[1]=ly;o[2]=lz; }
    #pragma unroll
    for (int j=0;j<8;++j){
      float dx=__fsub_rn(px[j],lx), dy=__fsub_rn(py[j],ly), dz=__fsub_rn(pz[j],lz);
      float dist=__fadd_rn(__fadd_rn(__fmul_rn(dx,dx),__fmul_rn(dy,dy)),__fmul_rn(dz,dz));
      d[j]=fminf(d[j],dist);
    }
    if (s==M_-1) break;
    float v=-1.0f; int vi=0x7fffffff;
    #pragma unroll
    for (int j=0;j<8;++j){ if (d[j]>v){ v=d[j]; vi=tid+256*j; } }
    #pragma unroll
    for (int off=32; off>0; off>>=1){
      float ov=__shfl_xor(v,off); int oi=__shfl_xor(vi,off);
      if (ov>v || (ov==v && oi<vi)){ v=ov; vi=oi; }
    }
    if (lane==0){ wv[wave]=v; wi[wave]=vi; }
    __syncthreads();
    if (tid==0){
      float bv=wv[0]; int bi=wi[0];
      for (int w=1;w<4;++w){ if (wv[w]>bv || (wv[w]==bv && wi[w]<bi)){ bv=wv[w]; bi=wi[w]; } }
      bc=bi;
    }
    __syncthreads();
    last=bc;
  }
}

// ---------------- K3: exact KNN (k smallest d2, stable ties) ----------------
template<int NP>
__global__ __launch_bounds__(64) void k_knn(const float* __restrict__ qp, const float* __restrict__ pool,
                                            int* __restrict__ out){
  constexpr int R = NP/64;
  int lane = threadIdx.x;
  int qm = blockIdx.x;            // b*M + m
  int b = qm / M_;
  const float* q = qp + (size_t)qm*3;
  float qx=q[0], qy=q[1], qz=q[2];
  float d2[R];
  #pragma unroll
  for (int j=0;j<R;++j){
    int n = lane + 64*j;
    const float* p = pool + ((size_t)b*NP + n)*3;
    float dx=__fsub_rn(qx,p[0]), dy=__fsub_rn(qy,p[1]), dz=__fsub_rn(qz,p[2]);
    d2[j]=__fadd_rn(__fadd_rn(__fmul_rn(dx,dx),__fmul_rn(dy,dy)),__fmul_rn(dz,dz));
  }
  for (int r=0;r<K_;++r){
    float v=FLT_MAX; int vi=0x7fffffff;
    #pragma unroll
    for (int j=0;j<R;++j){ if (d2[j]<v){ v=d2[j]; vi=lane+64*j; } }
    #pragma unroll
    for (int off=32; off>0; off>>=1){
      float ov=__shfl_xor(v,off); int oi=__shfl_xor(vi,off);
      if (ov<v || (ov==v && oi<vi)){ v=ov; vi=oi; }
    }
    if (lane==0) out[(size_t)qm*K_ + r] = vi;
    #pragma unroll
    for (int j=0;j<R;++j){ if (vi == lane + 64*j) d2[j] = FLT_MAX; }
  }
}

// ---------------- K4: fused down-proj + relu + neighbor-max -> xA [B,M,NG,C] ----------------
__global__ __launch_bounds__(256) void k_downmax(
    const float* __restrict__ x1, const int* __restrict__ nbrD,
    const float* __restrict__ dw, const float* __restrict__ db,
    float* __restrict__ xA){
  int bm = blockIdx.x; int b = bm / M_;
  int tid = threadIdx.x;
  __shared__ int nb[K_];
  __shared__ float xs[K_][NG_*H_];     // 48 KB
  if (tid<K_) nb[tid] = nbrD[(size_t)bm*K_ + tid];
  __syncthreads();
  for (int idx=tid; idx<K_*NG_*H_; idx+=256){
    int k = idx / (NG_*H_), r = idx % (NG_*H_);
    xs[k][r] = x1[((size_t)(b*N_) + nb[k])*(NG_*H_) + r];
  }
  __syncthreads();
  int c = tid & 127, gh = tid >> 7;
  float dbc = db[c];
  for (int gi=0; gi<6; ++gi){
    int g = gh*6 + gi;
    float acc[K_];
    #pragma unroll
    for (int k=0;k<K_;++k) acc[k]=dbc;
    for (int i4=0;i4<16;++i4){
      float w0 = dw[(i4*4+0)*C_ + c];
      float w1 = dw[(i4*4+1)*C_ + c];
      float w2 = dw[(i4*4+2)*C_ + c];
      float w3 = dw[(i4*4+3)*C_ + c];
      #pragma unroll
      for (int k=0;k<K_;++k){
        float4 xv = *(const float4*)&xs[k][g*H_ + i4*4];
        acc[k] = fmaf(xv.x,w0,fmaf(xv.y,w1,fmaf(xv.z,w2,fmaf(xv.w,w3,acc[k]))));
      }
    }
    float best = acc[0];
    #pragma unroll
    for (int k=1;k<K_;++k) best = fmaxf(best, acc[k]);
    xA[(size_t)bm*(NG_*C_) + g*C_ + c] = fmaxf(best, 0.0f);
  }
}

// ---------------- K5: kbR basis MLP [NG,NG,BD] ----------------
__global__ __launch_bounds__(128) void k_kbR(
    const float* __restrict__ grid, const float* __restrict__ rff,
    const float* __restrict__ w1, const float* __restrict__ b1,
    const float* __restrict__ w2, const float* __restrict__ b2,
    float* __restrict__ kbR){
  int gm = blockIdx.x / NG_, gn = blockIdx.x % NG_;
  int j = threadIdx.x;
  float z = grid[gm*3]*grid[gn*3] + grid[gm*3+1]*grid[gn*3+1] + grid[gm*3+2]*grid[gn*3+2];
  __shared__ float fs[128], hs[128];
  int jj = j & 63;
  float ang = 6.283185307179586f * (z * rff[jj]);
  fs[j] = (j<64) ? sinf(ang) : cosf(ang);
  __syncthreads();
  float acc = b1[j];
  for (int i=0;i<128;++i) acc = fmaf(fs[i], w1[i*128+j], acc);
  hs[j] = gelu_f(acc);
  __syncthreads();
  if (j < 64){
    float a2 = b2[j];
    for (int i=0;i<128;++i) a2 = fmaf(hs[i], w2[i*64+j], a2);
    kbR[(size_t)blockIdx.x*64 + j] = gelu_f(a2);
  }
}

// ---------------- K6: kR = kbR @ kR_w + b  [NG,NG,C] ----------------
__global__ __launch_bounds__(128) void k_kR(
    const float* __restrict__ kbR, const float* __restrict__ kRw, const float* __restrict__ kRb,
    float* __restrict__ kR){
  int pair = blockIdx.x; int c = threadIdx.x;
  __shared__ float kb[64];
  if (c<64) kb[c] = kbR[(size_t)pair*64 + c];
  __syncthreads();
  float acc = kRb[c];
  for (int d=0;d<64;++d) acc = fmaf(kb[d], kRw[d*128+c], acc);
  kR[(size_t)pair*128 + c] = acc;
}

// ---------------- K7: kbx basis MLP (big GEMM) -> [B*M*K*NG, BD] ----------------
__global__ __launch_bounds__(256) void k_kbx(
    const float* __restrict__ ps, const int* __restrict__ nbr,
    const float* __restrict__ grid, const float* __restrict__ rff,
    const float* __restrict__ w1, const float* __restrict__ b1,
    const float* __restrict__ w2, const float* __restrict__ b2,
    float* __restrict__ kbx){
  int tid = threadIdx.x;
  __shared__ float z0s[32], z1s[32];
  __shared__ float rw[128];
  __shared__ float Ft[128][32];       // 16 KB  (f-dim major, fiber minor)
  __shared__ float WcF[4096];         // 16 KB weight chunk
  __shared__ float Hs[32][129];       // 16.5 KB padded
  if (tid<128) rw[tid] = rff[tid];
  if (tid<32){
    int fid = blockIdx.x*32 + tid;
    int g = fid % NG_;
    int k = (fid/NG_) % K_;
    int bm = fid / (NG_*K_);          // b*M+m
    int b = bm / M_;
    int nb = nbr[(size_t)bm*K_ + k];
    const float* pm = ps + (size_t)bm*3;
    const float* pn = ps + ((size_t)(b*M_) + nb)*3;
    float rx = pn[0]-pm[0], ry = pn[1]-pm[1], rz3 = pn[2]-pm[2];
    const float* gg = grid + g*3;
    float rz = rx*gg[0] + ry*gg[1] + rz3*gg[2];
    float vx = rx - rz*gg[0], vy = ry - rz*gg[1], vz = rz3 - rz*gg[2];
    float rxy = sqrtf(vx*vx + vy*vy + vz*vz + 1e-12f);
    z0s[tid]=rxy; z1s[tid]=rz;
  }
  __syncthreads();
  { // Phase A: fill F (RFF features), transposed
    int f = tid & 31;
    int kb0 = (tid>>5)*16;
    float z0=z0s[f], z1=z1s[f];
    #pragma unroll
    for (int qq=0;qq<16;++qq){
      int kd = kb0+qq; int jj = kd & 63;
      float ang = 6.283185307179586f * (z0*rw[jj] + z1*rw[64+jj]);
      Ft[kd][f] = (kd<64) ? sinf(ang) : cosf(ang);
    }
  }
  // Phase B: H = gelu(F @ W1 + b1)
  int o = tid>>4, fg = tid&15;
  int j0 = o*8, f0 = fg*2;
  float acc[2][8];
  #pragma unroll
  for (int d=0; d<2; ++d)
    #pragma unroll
    for (int e=0;e<8;++e) acc[d][e]=0.f;
  const float4* w1v = (const float4*)w1;
  for (int kc=0;kc<4;++kc){
    __syncthreads();
    #pragma unroll
    for (int qq=0;qq<4;++qq){
      int slot = tid + qq*256;
      ((float4*)WcF)[slot] = w1v[kc*1024 + slot];
    }
    __syncthreads();
    #pragma unroll
    for (int kk=0;kk<32;++kk){
      float2 fv = *(const float2*)&Ft[kc*32+kk][f0];
      float w8[8];
      *(float4*)&w8[0] = *(const float4*)&WcF[kk*128 + j0];
      *(float4*)&w8[4] = *(const float4*)&WcF[kk*128 + j0 + 4];
      #pragma unroll
      for (int e=0;e<8;++e){
        acc[0][e] = fmaf(fv.x, w8[e], acc[0][e]);
        acc[1][e] = fmaf(fv.y, w8[e], acc[1][e]);
      }
    }
  }
  #pragma unroll
  for (int d=0;d<2;++d)
    #pragma unroll
    for (int e=0;e<8;++e)
      Hs[f0+d][j0+e] = gelu_f(b1[j0+e] + acc[d][e]);
  // Phase C: out = gelu(H @ W2 + b2)
  int f = tid & 31, co = tid>>5;
  int jc = co*8;
  float a2[8];
  #pragma unroll
  for (int e=0;e<8;++e) a2[e]=0.f;
  const float4* w2v = (const float4*)w2;
  for (int kc=0;kc<4;++kc){
    __syncthreads();
    #pragma unroll
    for (int qq=0;qq<2;++qq){
      int slot = tid + qq*256;
      ((float4*)WcF)[slot] = w2v[kc*512 + slot];
    }
    __syncthreads();
    #pragma unroll
    for (int kk=0;kk<32;++kk){
      float h = Hs[f][kc*32+kk];
      float w8[8];
      *(float4*)&w8[0] = *(const float4*)&WcF[kk*64 + jc];
      *(float4*)&w8[4] = *(const float4*)&WcF[kk*64 + jc + 4];
      #pragma unroll
      for (int e=0;e<8;++e) a2[e] = fmaf(h, w8[e], a2[e]);
    }
  }
  size_t fido = (size_t)blockIdx.x*32 + f;
  float o8[8];
  #pragma unroll
  for (int e=0;e<8;++e) o8[e] = gelu_f(b2[jc+e] + a2[e]);
  *(float4*)&kbx[fido*64 + jc]     = *(const float4*)&o8[0];
  *(float4*)&kbx[fido*64 + jc + 4] = *(const float4*)&o8[4];
}

// ---------------- K8: interaction layer ----------------
__global__ __launch_bounds__(256) void k_inter(
    const float* __restrict__ xin, const int* __restrict__ nbr,
    const float* __restrict__ kbx, const float* __restrict__ kR,
    const float* __restrict__ kxw, const float* __restrict__ kxb,
    const float* __restrict__ mw, const float* __restrict__ mb,
    float* __restrict__ xout){
  int bm = blockIdx.x; int b = bm / M_;
  int tid = threadIdx.x;
  int c = tid & 127, gh = tid >> 7;
  __shared__ float kbs[NG_*BD_];    // 3 KB
  __shared__ float xns[NG_*C_];     // 6 KB
  __shared__ float aggS[NG_][C_];   // 6 KB
  __shared__ float yS[NG_][C_];     // 6 KB
  float accg[6] = {0,0,0,0,0,0};
  float kxbc = kxb[c];
  for (int k=0;k<K_;++k){
    int nb = nbr[(size_t)bm*K_ + k];
    __syncthreads();
    for (int idx=tid; idx<NG_*BD_; idx+=256)
      kbs[idx] = kbx[((size_t)bm*K_ + k)*(NG_*BD_) + idx];
    for (int idx=tid; idx<NG_*C_; idx+=256)
      xns[idx] = xin[((size_t)(b*M_) + nb)*(NG_*C_) + idx];
    __syncthreads();
    float t6[6] = {0,0,0,0,0,0};
    for (int d4=0; d4<16; ++d4){
      float w0 = kxw[(d4*4+0)*C_+c], w1 = kxw[(d4*4+1)*C_+c],
            w2 = kxw[(d4*4+2)*C_+c], w3 = kxw[(d4*4+3)*C_+c];
      #pragma unroll
      for (int gi=0; gi<6; ++gi){
        int g = gh*6+gi;
        float4 kv = *(const float4*)&kbs[g*BD_ + d4*4];
        t6[gi] = fmaf(kv.x,w0,fmaf(kv.y,w1,fmaf(kv.z,w2,fmaf(kv.w,w3,t6[gi]))));
      }
    }
    #pragma unroll
    for (int gi=0; gi<6; ++gi){
      int g = gh*6+gi;
      accg[gi] = fmaf(t6[gi]+kxbc, xns[g*C_+c], accg[gi]);
    }
  }
  __syncthreads();
  #pragma unroll
  for (int gi=0; gi<6; ++gi)
    aggS[gh*6+gi][c] = accg[gi] * (1.0f/16.0f);
  __syncthreads();
  #pragma unroll
  for (int gi=0; gi<6; ++gi){
    int g = gh*6+gi;
    float yv = 0.f;
    #pragma unroll
    for (int n=0;n<NG_;++n) yv = fmaf(aggS[n][c], kR[((size_t)g*NG_+n)*C_ + c], yv);
    yS[g][c] = yv * (1.0f/12.0f);
  }
  __syncthreads();
  float m6[6] = {0,0,0,0,0,0};
  for (int i4=0;i4<32;++i4){
    float w0 = mw[(i4*4+0)*C_+c], w1 = mw[(i4*4+1)*C_+c],
          w2 = mw[(i4*4+2)*C_+c], w3 = mw[(i4*4+3)*C_+c];
    #pragma unroll
    for (int gi=0;gi<6;++gi){
      int g = gh*6+gi;
      float4 yv = *(const float4*)&yS[g][i4*4];
      m6[gi] = fmaf(yv.x,w0,fmaf(yv.y,w1,fmaf(yv.z,w2,fmaf(yv.w,w3,m6[gi]))));
    }
  }
  float mbc = mb[c];
  #pragma unroll
  for (int gi=0;gi<6;++gi){
    int g = gh*6+gi;
    size_t off = (size_t)bm*(NG_*C_) + g*C_ + c;
    xout[off] = xin[off] + gelu_f(m6[gi] + mbc);
  }
}

// ---------------- K9a: parallel partial reduction over rows of x ----------------
// grid: B*64 blocks, 256 threads. Each block sums 96 rows of [C] -> part[blk][C].
__global__ __launch_bounds__(256) void k_reduce(
    const float* __restrict__ x, float* __restrict__ part){
  int blk = blockIdx.x;
  int b = blk >> 6, ch = blk & 63;
  int tid = threadIdx.x;
  int c = tid & 127, half = tid >> 7;
  const float* xb = x + (size_t)b*(M_*NG_)*C_;
  int r0 = ch*96;
  float acc = 0.f;
  for (int r = r0 + half; r < r0 + 96; r += 2)
    acc += xb[(size_t)r*C_ + c];
  __shared__ float red[256];
  red[tid] = acc;
  __syncthreads();
  if (half == 0)
    part[(size_t)blk*C_ + c] = red[c] + red[128 + c];
}

// ---------------- K9b: final reduce + MLP head ----------------
__global__ __launch_bounds__(256) void k_head(
    const float* __restrict__ part,
    const float* __restrict__ p1w, const float* __restrict__ p1b,
    const float* __restrict__ p2w, const float* __restrict__ p2b,
    const float* __restrict__ p3w, const float* __restrict__ p3b,
    float* __restrict__ out){
  int b = blockIdx.x, tid = threadIdx.x;
  __shared__ float gs[128];
  if (tid < 128){
    float a = 0.f;
    const float* pb = part + (size_t)b*64*C_;
    for (int ch = 0; ch < 64; ++ch) a += pb[(size_t)ch*C_ + tid];
    gs[tid] = a * (1.0f/(M_*NG_));
  }
  __syncthreads();
  __shared__ float h1[256];
  {
    float a = p1b[tid];
    for (int i=0;i<128;++i) a = fmaf(gs[i], p1w[i*256+tid], a);
    h1[tid] = gelu_f(a);
  }
  __syncthreads();
  __shared__ float h2[64];
  if (tid<64){
    float a = p2b[tid];
    for (int i=0;i<256;++i) a = fmaf(h1[i], p2w[i*64+tid], a);
    h2[tid] = gelu_f(a);
  }
  __syncthreads();
  if (tid==0){
    float a = p3b[0];
    for (int i=0;i<64;++i) a = fmaf(h2[i], p3w[i], a);
    out[b] = a;
  }
}

extern "C" void kernel_launch(void* const* d_in, const int* in_sizes, int n_in,
                              void* d_out, int out_size, void* d_ws, size_t ws_size,
                              hipStream_t stream){
  const float* pos    = (const float*)d_in[0];
  const float* normal = (const float*)d_in[1];
  const float* grid   = (const float*)d_in[2];
  const float* e1w = (const float*)d_in[3];  const float* e1b = (const float*)d_in[4];
  const float* e2w = (const float*)d_in[5];  const float* e2b = (const float*)d_in[6];
  const float* dww = (const float*)d_in[7];  const float* dwb = (const float*)d_in[8];
  const float* bx_rff = (const float*)d_in[9];
  const float* bx1w = (const float*)d_in[10]; const float* bx1b = (const float*)d_in[11];
  const float* bx2w = (const float*)d_in[12]; const float* bx2b = (const float*)d_in[13];
  const float* bR_rff = (const float*)d_in[14];
  const float* bR1w = (const float*)d_in[15]; const float* bR1b = (const float*)d_in[16];
  const float* bR2w = (const float*)d_in[17]; const float* bR2b = (const float*)d_in[18];
  const float* i1kxw = (const float*)d_in[19]; const float* i1kxb = (const float*)d_in[20];
  const float* i1kRw = (const float*)d_in[21]; const float* i1kRb = (const float*)d_in[22];
  const float* i1mw  = (const float*)d_in[23]; const float* i1mb  = (const float*)d_in[24];
  const float* i2kxw = (const float*)d_in[25]; const float* i2kxb = (const float*)d_in[26];
  const float* i2kRw = (const float*)d_in[27]; const float* i2kRb = (const float*)d_in[28];
  const float* i2mw  = (const float*)d_in[29]; const float* i2mb  = (const float*)d_in[30];
  const float* p1w = (const float*)d_in[31]; const float* p1b = (const float*)d_in[32];
  const float* p2w = (const float*)d_in[33]; const float* p2b = (const float*)d_in[34];
  const float* p3w = (const float*)d_in[35]; const float* p3b = (const float*)d_in[36];
  float* out = (float*)d_out;

  float* ws = (float*)d_ws;
  size_t o = 0;
  float* x1  = ws + o; o += (size_t)B_*N_*NG_*H_;       // 6,291,456
  float* psb = ws + o; o += (size_t)B_*M_*3;            // 6,144
  float* xA  = ws + o; o += (size_t)B_*M_*NG_*C_;       // 3,145,728
  float* xB  = ws + o; o += (size_t)B_*M_*NG_*C_;       // 3,145,728
  float* kbx = ws + o; o += (size_t)B_*M_*K_*NG_*BD_;   // 25,165,824
  float* kbR = ws + o; o += (size_t)NG_*NG_*BD_;        // 9,216
  float* kRb = ws + o; o += (size_t)NG_*NG_*C_;         // 18,432
  float* part = ws + o; o += (size_t)B_*64*C_;          // 32,768
  int* nbrD  = (int*)(ws + o); o += (size_t)B_*M_*K_;   // 32,768
  int* nbrS  = (int*)(ws + o); o += (size_t)B_*M_*K_;   // 32,768

  k_lift<<<B_*N_*NG_/4, 256, 0, stream>>>(pos, normal, grid, e1w,e1b,e2w,e2b, x1);
  k_fps<<<B_, 256, 0, stream>>>(pos, psb);
  k_knn<N_><<<B_*M_, 64, 0, stream>>>(psb, pos, nbrD);
  k_knn<M_><<<B_*M_, 64, 0, stream>>>(psb, psb, nbrS);
  k_downmax<<<B_*M_, 256, 0, stream>>>(x1, nbrD, dww, dwb, xA);
  k_kbR<<<NG_*NG_, 128, 0, stream>>>(grid, bR_rff, bR1w, bR1b, bR2w, bR2b, kbR);
  k_kbx<<<(B_*M_*K_*NG_)/32, 256, 0, stream>>>(psb, nbrS, grid, bx_rff, bx1w, bx1b, bx2w, bx2b, kbx);
  k_kR<<<NG_*NG_, 128, 0, stream>>>(kbR, i1kRw, i1kRb, kRb);
  k_inter<<<B_*M_, 256, 0, stream>>>(xA, nbrS, kbx, kRb, i1kxw, i1kxb, i1mw, i1mb, xB);
  k_kR<<<NG_*NG_, 128, 0, stream>>>(kbR, i2kRw, i2kRb, kRb);
  k_inter<<<B_*M_, 256, 0, stream>>>(xB, nbrS, kbx, kRb, i2kxw, i2kxb, i2mw, i2mb, xA);
  k_reduce<<<B_*64, 256, 0, stream>>>(xA, part);
  k_head<<<B_, 256, 0, stream>>>(part, p1w,p1b,p2w,p2b,p3w,p3b, out);
}

// Round 3
// 1387.071 us; speedup vs baseline: 1.9177x; 1.3980x over previous
//
#include <hip/hip_runtime.h>
#include <hip/hip_bf16.h>
#include <cfloat>

#define B_ 4
#define N_ 2048
#define NG_ 12
#define K_ 16
#define H_ 64
#define C_ 128
#define BD_ 64
#define M_ 512

typedef __attribute__((ext_vector_type(8))) short short8;
typedef __attribute__((ext_vector_type(4))) float floatx4;
typedef unsigned short ushort_t;
typedef unsigned int uint_t;

__device__ __forceinline__ float gelu_f(float x){
  // tanh-approx gelu via exp (matches jax.nn.gelu approximate=True to ~1e-6)
  float s = 0.7978845608028654f*(x + 0.044715f*x*x*x);
  float e = __expf(2.0f*s);
  float t = 1.0f - 2.0f/(e + 1.0f);
  return 0.5f*x*(1.0f + t);
}

__device__ __forceinline__ ushort_t bf16_rne(float x){
  uint_t u = __float_as_uint(x);
  uint_t r = (u + 0x7fffu + ((u >> 16) & 1u)) >> 16;
  return (ushort_t)r;
}

// ---------------- K1: lift + embed -> x1 [B,N,NG,H] ----------------
__global__ __launch_bounds__(256) void k_lift(
    const float* __restrict__ pos, const float* __restrict__ normal,
    const float* __restrict__ grid,
    const float* __restrict__ e1w, const float* __restrict__ e1b,
    const float* __restrict__ e2w, const float* __restrict__ e2b,
    float* __restrict__ x1){
  int tid = threadIdx.x;
  int q = tid>>6, lane = tid&63;
  int fid = blockIdx.x*4 + q;
  int g = fid % NG_;
  int n = (fid / NG_) % N_;
  int b = fid / (NG_*N_);
  const float* nm = normal + (size_t)(b*N_+n)*3;
  const float* pp = pos + (size_t)(b*N_+n)*3;
  const float* gg = grid + g*3;
  float f0 = nm[0]*gg[0] + nm[1]*gg[1] + nm[2]*gg[2];
  float t = e1b[lane] + f0*e1w[lane] + pp[0]*e1w[64+lane] + pp[1]*e1w[128+lane] + pp[2]*e1w[192+lane];
  __shared__ float ts[4][64];
  ts[q][lane] = gelu_f(t);
  __syncthreads();
  float acc = e2b[lane];
  #pragma unroll
  for (int i=0;i<64;++i) acc = fmaf(ts[q][i], e2w[i*64+lane], acc);
  x1[(size_t)fid*64 + lane] = acc;
}

// ---------------- K2: farthest point sampling -> ps [B,M,3] ----------------
__global__ __launch_bounds__(256) void k_fps(const float* __restrict__ pos, float* __restrict__ ps){
  int b = blockIdx.x, tid = threadIdx.x;
  __shared__ float posS[N_*3];
  for (int i=tid;i<N_*3;i+=256) posS[i] = pos[(size_t)b*N_*3 + i];
  __syncthreads();
  float px[8],py[8],pz[8],d[8];
  #pragma unroll
  for (int j=0;j<8;++j){
    int n = tid + 256*j;
    px[j]=posS[n*3]; py[j]=posS[n*3+1]; pz[j]=posS[n*3+2];
    d[j]=1e10f;
  }
  __shared__ float wv[4]; __shared__ int wi[4]; __shared__ int bc;
  int wave = tid>>6, lane = tid&63;
  int last = 0;
  for (int s=0;s<M_;++s){
    float lx=posS[last*3], ly=posS[last*3+1], lz=posS[last*3+2];
    if (tid==0){ float* o = ps + ((size_t)b*M_+s)*3; o[0]=lx;o[1]=ly;o[2]=lz; }
    #pragma unroll
    for (int j=0;j<8;++j){
      float dx=__fsub_rn(px[j],lx), dy=__fsub_rn(py[j],ly), dz=__fsub_rn(pz[j],lz);
      float dist=__fadd_rn(__fadd_rn(__fmul_rn(dx,dx),__fmul_rn(dy,dy)),__fmul_rn(dz,dz));
      d[j]=fminf(d[j],dist);
    }
    if (s==M_-1) break;
    float v=-1.0f; int vi=0x7fffffff;
    #pragma unroll
    for (int j=0;j<8;++j){ if (d[j]>v){ v=d[j]; vi=tid+256*j; } }
    #pragma unroll
    for (int off=32; off>0; off>>=1){
      float ov=__shfl_xor(v,off); int oi=__shfl_xor(vi,off);
      if (ov>v || (ov==v && oi<vi)){ v=ov; vi=oi; }
    }
    if (lane==0){ wv[wave]=v; wi[wave]=vi; }
    __syncthreads();
    if (tid==0){
      float bv=wv[0]; int bi=wi[0];
      for (int w=1;w<4;++w){ if (wv[w]>bv || (wv[w]==bv && wi[w]<bi)){ bv=wv[w]; bi=wi[w]; } }
      bc=bi;
    }
    __syncthreads();
    last=bc;
  }
}

// ---------------- K3: exact KNN (k smallest d2, stable ties) ----------------
template<int NP>
__global__ __launch_bounds__(64) void k_knn(const float* __restrict__ qp, const float* __restrict__ pool,
                                            int* __restrict__ out){
  constexpr int R = NP/64;
  int lane = threadIdx.x;
  int qm = blockIdx.x;            // b*M + m
  int b = qm / M_;
  const float* q = qp + (size_t)qm*3;
  float qx=q[0], qy=q[1], qz=q[2];
  float d2[R];
  #pragma unroll
  for (int j=0;j<R;++j){
    int n = lane + 64*j;
    const float* p = pool + ((size_t)b*NP + n)*3;
    float dx=__fsub_rn(qx,p[0]), dy=__fsub_rn(qy,p[1]), dz=__fsub_rn(qz,p[2]);
    d2[j]=__fadd_rn(__fadd_rn(__fmul_rn(dx,dx),__fmul_rn(dy,dy)),__fmul_rn(dz,dz));
  }
  for (int r=0;r<K_;++r){
    float v=FLT_MAX; int vi=0x7fffffff;
    #pragma unroll
    for (int j=0;j<R;++j){ if (d2[j]<v){ v=d2[j]; vi=lane+64*j; } }
    #pragma unroll
    for (int off=32; off>0; off>>=1){
      float ov=__shfl_xor(v,off); int oi=__shfl_xor(vi,off);
      if (ov<v || (ov==v && oi<vi)){ v=ov; vi=oi; }
    }
    if (lane==0) out[(size_t)qm*K_ + r] = vi;
    #pragma unroll
    for (int j=0;j<R;++j){ if (vi == lane + 64*j) d2[j] = FLT_MAX; }
  }
}

// ---------------- K4: fused down-proj + relu + neighbor-max -> xA [B,M,NG,C] ----------------
__global__ __launch_bounds__(256) void k_downmax(
    const float* __restrict__ x1, const int* __restrict__ nbrD,
    const float* __restrict__ dw, const float* __restrict__ db,
    float* __restrict__ xA){
  int bm = blockIdx.x; int b = bm / M_;
  int tid = threadIdx.x;
  __shared__ int nb[K_];
  __shared__ float xs[K_][NG_*H_];     // 48 KB
  if (tid<K_) nb[tid] = nbrD[(size_t)bm*K_ + tid];
  __syncthreads();
  for (int idx=tid; idx<K_*NG_*H_/4; idx+=256){
    int k = idx / (NG_*H_/4), r = idx % (NG_*H_/4);
    ((float4*)&xs[k][0])[r] = ((const float4*)&x1[((size_t)(b*N_) + nb[k])*(NG_*H_)])[r];
  }
  __syncthreads();
  int c = tid & 127, gh = tid >> 7;
  float dbc = db[c];
  for (int gi=0; gi<6; ++gi){
    int g = gh*6 + gi;
    float acc[K_];
    #pragma unroll
    for (int k=0;k<K_;++k) acc[k]=dbc;
    for (int i4=0;i4<16;++i4){
      float w0 = dw[(i4*4+0)*C_ + c];
      float w1 = dw[(i4*4+1)*C_ + c];
      float w2 = dw[(i4*4+2)*C_ + c];
      float w3 = dw[(i4*4+3)*C_ + c];
      #pragma unroll
      for (int k=0;k<K_;++k){
        float4 xv = *(const float4*)&xs[k][g*H_ + i4*4];
        acc[k] = fmaf(xv.x,w0,fmaf(xv.y,w1,fmaf(xv.z,w2,fmaf(xv.w,w3,acc[k]))));
      }
    }
    float best = acc[0];
    #pragma unroll
    for (int k=1;k<K_;++k) best = fmaxf(best, acc[k]);
    xA[(size_t)bm*(NG_*C_) + g*C_ + c] = fmaxf(best, 0.0f);
  }
}

// ---------------- K5: kbR basis MLP [NG,NG,BD] ----------------
__global__ __launch_bounds__(128) void k_kbR(
    const float* __restrict__ grid, const float* __restrict__ rff,
    const float* __restrict__ w1, const float* __restrict__ b1,
    const float* __restrict__ w2, const float* __restrict__ b2,
    float* __restrict__ kbR){
  int gm = blockIdx.x / NG_, gn = blockIdx.x % NG_;
  int j = threadIdx.x;
  float z = grid[gm*3]*grid[gn*3] + grid[gm*3+1]*grid[gn*3+1] + grid[gm*3+2]*grid[gn*3+2];
  __shared__ float fs[128], hs[128];
  int jj = j & 63;
  float ang = 6.283185307179586f * (z * rff[jj]);
  fs[j] = (j<64) ? sinf(ang) : cosf(ang);
  __syncthreads();
  float acc = b1[j];
  for (int i=0;i<128;++i) acc = fmaf(fs[i], w1[i*128+j], acc);
  hs[j] = gelu_f(acc);
  __syncthreads();
  if (j < 64){
    float a2 = b2[j];
    for (int i=0;i<128;++i) a2 = fmaf(hs[i], w2[i*64+j], a2);
    kbR[(size_t)blockIdx.x*64 + j] = gelu_f(a2);
  }
}

// ---------------- K6: kR = kbR @ kR_w + b  [NG,NG,C] ----------------
__global__ __launch_bounds__(128) void k_kR(
    const float* __restrict__ kbR, const float* __restrict__ kRw, const float* __restrict__ kRb,
    float* __restrict__ kR){
  int pair = blockIdx.x; int c = threadIdx.x;
  __shared__ float kb[64];
  if (c<64) kb[c] = kbR[(size_t)pair*64 + c];
  __syncthreads();
  float acc = kRb[c];
  for (int d=0;d<64;++d) acc = fmaf(kb[d], kRw[d*128+c], acc);
  kR[(size_t)pair*128 + c] = acc;
}

// ---------------- K6b: split weights into transposed bf16 hi/lo ----------------
__global__ __launch_bounds__(256) void k_wsplit(
    const float* __restrict__ w1, const float* __restrict__ w2,
    ushort_t* __restrict__ w1hiT, ushort_t* __restrict__ w1loT,
    ushort_t* __restrict__ w2hiT, ushort_t* __restrict__ w2loT){
  int tid = blockIdx.x*256 + threadIdx.x;
  if (tid < 16384){
    int j = tid >> 7, k = tid & 127;
    float x = w1[k*128 + j];
    ushort_t hi = bf16_rne(x);
    float hif = __uint_as_float(((uint_t)hi)<<16);
    ushort_t lo = bf16_rne(x - hif);
    w1hiT[tid] = hi; w1loT[tid] = lo;
  }
  if (tid < 8192){
    int c = tid >> 7, j = tid & 127;
    float x = w2[j*64 + c];
    ushort_t hi = bf16_rne(x);
    float hif = __uint_as_float(((uint_t)hi)<<16);
    ushort_t lo = bf16_rne(x - hif);
    w2hiT[tid] = hi; w2loT[tid] = lo;
  }
}

// ---------------- K7: kbx basis MLP via MFMA bf16 x3 (hi/lo split) ----------------
// block = 256 thr = 4 waves; each wave owns 32 fibers; block = 128 fibers.
__global__ __launch_bounds__(256) void k_kbx(
    const float* __restrict__ ps, const int* __restrict__ nbr,
    const float* __restrict__ grid, const float* __restrict__ rff,
    const ushort_t* __restrict__ w1hiT, const ushort_t* __restrict__ w1loT,
    const ushort_t* __restrict__ w2hiT, const ushort_t* __restrict__ w2loT,
    const float* __restrict__ b1, const float* __restrict__ b2,
    float* __restrict__ kbx){
  __shared__ float z0s[128], z1s[128], rws[128];
  __shared__ float bounce[4][32*34];
  int tid = threadIdx.x;
  if (tid < 128){
    rws[tid] = rff[tid];
    int fid = blockIdx.x*128 + tid;
    int g = fid % NG_;
    int k = (fid/NG_) % K_;
    int bm = fid / (NG_*K_);
    int b = bm / M_;
    int nb = nbr[(size_t)bm*K_ + k];
    const float* pm = ps + (size_t)bm*3;
    const float* pn = ps + ((size_t)(b*M_) + nb)*3;
    float rx = pn[0]-pm[0], ry = pn[1]-pm[1], rz3 = pn[2]-pm[2];
    const float* gg = grid + g*3;
    float rz = rx*gg[0] + ry*gg[1] + rz3*gg[2];
    float vx = rx - rz*gg[0], vy = ry - rz*gg[1], vz = rz3 - rz*gg[2];
    float rxy = sqrtf(vx*vx + vy*vy + vz*vz + 1e-12f);
    z0s[tid]=rxy; z1s[tid]=rz;
  }
  __syncthreads();
  int wid = tid>>6, lane = tid&63;
  int ln = lane & 15, g = lane >> 4;

  // ---- A fragments (RFF features), computed fully in registers ----
  short8 ahi[2][4], alo[2][4];
  #pragma unroll
  for (int rt=0; rt<2; ++rt){
    float z0 = z0s[wid*32 + rt*16 + ln];
    float z1 = z1s[wid*32 + rt*16 + ln];
    #pragma unroll
    for (int ks=0; ks<4; ++ks){
      #pragma unroll
      for (int e=0; e<8; ++e){
        int kd = ks*32 + g*8 + e;
        int kk = kd & 63;
        float t = z0*rws[kk] + z1*rws[64+kk];
        t = t - floorf(t);
        float v = (ks < 2) ? __builtin_amdgcn_sinf(t) : __builtin_amdgcn_cosf(t);
        ushort_t hi = bf16_rne(v);
        float hif = __uint_as_float(((uint_t)hi)<<16);
        ushort_t lo = bf16_rne(v - hif);
        ahi[rt][ks][e] = (short)hi;
        alo[rt][ks][e] = (short)lo;
      }
    }
  }

  floatx4 acc2[2][4];
  #pragma unroll
  for (int rt=0; rt<2; ++rt)
    #pragma unroll
    for (int ct=0; ct<4; ++ct)
      acc2[rt][ct] = (floatx4){0.f,0.f,0.f,0.f};

  float* bw = &bounce[wid][0];

  #pragma unroll
  for (int jp=0; jp<4; ++jp){
    // ---- GEMM1 partial: 32 output cols (jp*32 .. +32) ----
    floatx4 acc1[2][2];
    #pragma unroll
    for (int rt=0; rt<2; ++rt)
      #pragma unroll
      for (int jt=0; jt<2; ++jt)
        acc1[rt][jt] = (floatx4){0.f,0.f,0.f,0.f};
    #pragma unroll
    for (int ks=0; ks<4; ++ks){
      #pragma unroll
      for (int jt=0; jt<2; ++jt){
        int j = jp*32 + jt*16 + ln;
        short8 bhi = *(const short8*)&w1hiT[(size_t)j*128 + ks*32 + g*8];
        short8 blo = *(const short8*)&w1loT[(size_t)j*128 + ks*32 + g*8];
        #pragma unroll
        for (int rt=0; rt<2; ++rt){
          acc1[rt][jt] = __builtin_amdgcn_mfma_f32_16x16x32_bf16(ahi[rt][ks], bhi, acc1[rt][jt], 0,0,0);
          acc1[rt][jt] = __builtin_amdgcn_mfma_f32_16x16x32_bf16(alo[rt][ks], bhi, acc1[rt][jt], 0,0,0);
          acc1[rt][jt] = __builtin_amdgcn_mfma_f32_16x16x32_bf16(ahi[rt][ks], blo, acc1[rt][jt], 0,0,0);
        }
      }
    }
    // ---- gelu + bounce to LDS (wave-private, no barrier needed) ----
    #pragma unroll
    for (int jt=0; jt<2; ++jt){
      float bb = b1[jp*32 + jt*16 + ln];
      #pragma unroll
      for (int rt=0; rt<2; ++rt)
        #pragma unroll
        for (int i=0; i<4; ++i)
          bw[(rt*16 + g*4 + i)*34 + jt*16 + ln] = gelu_f(bb + acc1[rt][jt][i]);
    }
    // ---- GEMM2 partial: contract these 32 j's ----
    #pragma unroll
    for (int rt=0; rt<2; ++rt){
      int base = (rt*16 + ln)*34 + g*8;
      float2 p0 = *(float2*)&bw[base+0];
      float2 p1 = *(float2*)&bw[base+2];
      float2 p2 = *(float2*)&bw[base+4];
      float2 p3 = *(float2*)&bw[base+6];
      float hv[8] = {p0.x,p0.y,p1.x,p1.y,p2.x,p2.y,p3.x,p3.y};
      short8 a2h, a2l;
      #pragma unroll
      for (int e=0; e<8; ++e){
        ushort_t hi = bf16_rne(hv[e]);
        float hif = __uint_as_float(((uint_t)hi)<<16);
        ushort_t lo = bf16_rne(hv[e] - hif);
        a2h[e] = (short)hi;
        a2l[e] = (short)lo;
      }
      #pragma unroll
      for (int ct=0; ct<4; ++ct){
        short8 b2h = *(const short8*)&w2hiT[(size_t)(ct*16+ln)*128 + jp*32 + g*8];
        short8 b2l = *(const short8*)&w2loT[(size_t)(ct*16+ln)*128 + jp*32 + g*8];
        acc2[rt][ct] = __builtin_amdgcn_mfma_f32_16x16x32_bf16(a2h, b2h, acc2[rt][ct], 0,0,0);
        acc2[rt][ct] = __builtin_amdgcn_mfma_f32_16x16x32_bf16(a2l, b2h, acc2[rt][ct], 0,0,0);
        acc2[rt][ct] = __builtin_amdgcn_mfma_f32_16x16x32_bf16(a2h, b2l, acc2[rt][ct], 0,0,0);
      }
    }
  }
  // ---- epilogue: gelu + store ----
  #pragma unroll
  for (int ct=0; ct<4; ++ct){
    float bb = b2[ct*16 + ln];
    #pragma unroll
    for (int rt=0; rt<2; ++rt)
      #pragma unroll
      for (int i=0; i<4; ++i){
        int row = wid*32 + rt*16 + g*4 + i;
        size_t fiber = (size_t)blockIdx.x*128 + row;
        kbx[fiber*64 + ct*16 + ln] = gelu_f(bb + acc2[rt][ct][i]);
      }
  }
}

// ---------------- K8: interaction layer ----------------
__global__ __launch_bounds__(256) void k_inter(
    const float* __restrict__ xin, const int* __restrict__ nbr,
    const float* __restrict__ kbx, const float* __restrict__ kR,
    const float* __restrict__ kxw, const float* __restrict__ kxb,
    const float* __restrict__ mw, const float* __restrict__ mb,
    float* __restrict__ xout){
  int bm = blockIdx.x; int b = bm / M_;
  int tid = threadIdx.x;
  int c = tid & 127, gh = tid >> 7;
  __shared__ float kbs[NG_*BD_];    // 3 KB
  __shared__ float xns[NG_*C_];     // 6 KB
  __shared__ float aggS[NG_][C_];   // 6 KB
  __shared__ float yS[NG_][C_];     // 6 KB
  // hoist kxw column into registers (reused across all 16 k iterations)
  float wreg[64];
  #pragma unroll
  for (int d=0; d<64; ++d) wreg[d] = kxw[d*C_ + c];
  float accg[6] = {0,0,0,0,0,0};
  float kxbc = kxb[c];
  for (int k=0;k<K_;++k){
    int nb = nbr[(size_t)bm*K_ + k];
    __syncthreads();
    {
      const float4* src = (const float4*)&kbx[((size_t)bm*K_ + k)*(NG_*BD_)];
      for (int idx=tid; idx<NG_*BD_/4; idx+=256) ((float4*)kbs)[idx] = src[idx];
      const float4* src2 = (const float4*)&xin[((size_t)(b*M_) + nb)*(NG_*C_)];
      for (int idx=tid; idx<NG_*C_/4; idx+=256) ((float4*)xns)[idx] = src2[idx];
    }
    __syncthreads();
    float t6[6] = {0,0,0,0,0,0};
    #pragma unroll
    for (int d4=0; d4<16; ++d4){
      #pragma unroll
      for (int gi=0; gi<6; ++gi){
        int g = gh*6+gi;
        float4 kv = *(const float4*)&kbs[g*BD_ + d4*4];
        t6[gi] = fmaf(kv.x,wreg[d4*4+0],fmaf(kv.y,wreg[d4*4+1],fmaf(kv.z,wreg[d4*4+2],fmaf(kv.w,wreg[d4*4+3],t6[gi]))));
      }
    }
    #pragma unroll
    for (int gi=0; gi<6; ++gi){
      int g = gh*6+gi;
      accg[gi] = fmaf(t6[gi]+kxbc, xns[g*C_+c], accg[gi]);
    }
  }
  __syncthreads();
  #pragma unroll
  for (int gi=0; gi<6; ++gi)
    aggS[gh*6+gi][c] = accg[gi] * (1.0f/16.0f);
  __syncthreads();
  #pragma unroll
  for (int gi=0; gi<6; ++gi){
    int g = gh*6+gi;
    float yv = 0.f;
    #pragma unroll
    for (int n=0;n<NG_;++n) yv = fmaf(aggS[n][c], kR[((size_t)g*NG_+n)*C_ + c], yv);
    yS[g][c] = yv * (1.0f/12.0f);
  }
  __syncthreads();
  float m6[6] = {0,0,0,0,0,0};
  for (int i4=0;i4<32;++i4){
    float w0 = mw[(i4*4+0)*C_+c], w1 = mw[(i4*4+1)*C_+c],
          w2 = mw[(i4*4+2)*C_+c], w3 = mw[(i4*4+3)*C_+c];
    #pragma unroll
    for (int gi=0;gi<6;++gi){
      int g = gh*6+gi;
      float4 yv = *(const float4*)&yS[g][i4*4];
      m6[gi] = fmaf(yv.x,w0,fmaf(yv.y,w1,fmaf(yv.z,w2,fmaf(yv.w,w3,m6[gi]))));
    }
  }
  float mbc = mb[c];
  #pragma unroll
  for (int gi=0;gi<6;++gi){
    int g = gh*6+gi;
    size_t off = (size_t)bm*(NG_*C_) + g*C_ + c;
    xout[off] = xin[off] + gelu_f(m6[gi] + mbc);
  }
}

// ---------------- K9a: parallel partial reduction ----------------
__global__ __launch_bounds__(256) void k_reduce(
    const float* __restrict__ x, float* __restrict__ part){
  int blk = blockIdx.x;
  int b = blk >> 6, ch = blk & 63;
  int tid = threadIdx.x;
  int c = tid & 127, half = tid >> 7;
  const float* xb = x + (size_t)b*(M_*NG_)*C_;
  int r0 = ch*96;
  float acc = 0.f;
  for (int r = r0 + half; r < r0 + 96; r += 2)
    acc += xb[(size_t)r*C_ + c];
  __shared__ float red[256];
  red[tid] = acc;
  __syncthreads();
  if (half == 0)
    part[(size_t)blk*C_ + c] = red[c] + red[128 + c];
}

// ---------------- K9b: final reduce + MLP head ----------------
__global__ __launch_bounds__(256) void k_head(
    const float* __restrict__ part,
    const float* __restrict__ p1w, const float* __restrict__ p1b,
    const float* __restrict__ p2w, const float* __restrict__ p2b,
    const float* __restrict__ p3w, const float* __restrict__ p3b,
    float* __restrict__ out){
  int b = blockIdx.x, tid = threadIdx.x;
  __shared__ float gs[128];
  if (tid < 128){
    float a = 0.f;
    const float* pb = part + (size_t)b*64*C_;
    for (int ch = 0; ch < 64; ++ch) a += pb[(size_t)ch*C_ + tid];
    gs[tid] = a * (1.0f/(M_*NG_));
  }
  __syncthreads();
  __shared__ float h1[256];
  {
    float a = p1b[tid];
    for (int i=0;i<128;++i) a = fmaf(gs[i], p1w[i*256+tid], a);
    h1[tid] = gelu_f(a);
  }
  __syncthreads();
  __shared__ float h2[64];
  if (tid<64){
    float a = p2b[tid];
    for (int i=0;i<256;++i) a = fmaf(h1[i], p2w[i*64+tid], a);
    h2[tid] = gelu_f(a);
  }
  __syncthreads();
  if (tid==0){
    float a = p3b[0];
    for (int i=0;i<64;++i) a = fmaf(h2[i], p3w[i], a);
    out[b] = a;
  }
}

extern "C" void kernel_launch(void* const* d_in, const int* in_sizes, int n_in,
                              void* d_out, int out_size, void* d_ws, size_t ws_size,
                              hipStream_t stream){
  const float* pos    = (const float*)d_in[0];
  const float* normal = (const float*)d_in[1];
  const float* grid   = (const float*)d_in[2];
  const float* e1w = (const float*)d_in[3];  const float* e1b = (const float*)d_in[4];
  const float* e2w = (const float*)d_in[5];  const float* e2b = (const float*)d_in[6];
  const float* dww = (const float*)d_in[7];  const float* dwb = (const float*)d_in[8];
  const float* bx_rff = (const float*)d_in[9];
  const float* bx1w = (const float*)d_in[10]; const float* bx1b = (const float*)d_in[11];
  const float* bx2w = (const float*)d_in[12]; const float* bx2b = (const float*)d_in[13];
  const float* bR_rff = (const float*)d_in[14];
  const float* bR1w = (const float*)d_in[15]; const float* bR1b = (const float*)d_in[16];
  const float* bR2w = (const float*)d_in[17]; const float* bR2b = (const float*)d_in[18];
  const float* i1kxw = (const float*)d_in[19]; const float* i1kxb = (const float*)d_in[20];
  const float* i1kRw = (const float*)d_in[21]; const float* i1kRb = (const float*)d_in[22];
  const float* i1mw  = (const float*)d_in[23]; const float* i1mb  = (const float*)d_in[24];
  const float* i2kxw = (const float*)d_in[25]; const float* i2kxb = (const float*)d_in[26];
  const float* i2kRw = (const float*)d_in[27]; const float* i2kRb = (const float*)d_in[28];
  const float* i2mw  = (const float*)d_in[29]; const float* i2mb  = (const float*)d_in[30];
  const float* p1w = (const float*)d_in[31]; const float* p1b = (const float*)d_in[32];
  const float* p2w = (const float*)d_in[33]; const float* p2b = (const float*)d_in[34];
  const float* p3w = (const float*)d_in[35]; const float* p3b = (const float*)d_in[36];
  float* out = (float*)d_out;

  float* ws = (float*)d_ws;
  size_t o = 0;
  float* x1  = ws + o; o += (size_t)B_*N_*NG_*H_;       // 6,291,456
  float* psb = ws + o; o += (size_t)B_*M_*3;            // 6,144
  float* xA  = ws + o; o += (size_t)B_*M_*NG_*C_;       // 3,145,728
  float* xB  = ws + o; o += (size_t)B_*M_*NG_*C_;       // 3,145,728
  float* kbx = ws + o; o += (size_t)B_*M_*K_*NG_*BD_;   // 25,165,824
  float* kbR = ws + o; o += (size_t)NG_*NG_*BD_;        // 9,216
  float* kRb = ws + o; o += (size_t)NG_*NG_*C_;         // 18,432
  float* part = ws + o; o += (size_t)B_*64*C_;          // 32,768
  int* nbrD  = (int*)(ws + o); o += (size_t)B_*M_*K_;   // 32,768
  int* nbrS  = (int*)(ws + o); o += (size_t)B_*M_*K_;   // 32,768
  ushort_t* w1hiT = (ushort_t*)(ws + o); o += 8192;     // 16384 ushort
  ushort_t* w1loT = (ushort_t*)(ws + o); o += 8192;
  ushort_t* w2hiT = (ushort_t*)(ws + o); o += 4096;     // 8192 ushort
  ushort_t* w2loT = (ushort_t*)(ws + o); o += 4096;

  k_lift<<<B_*N_*NG_/4, 256, 0, stream>>>(pos, normal, grid, e1w,e1b,e2w,e2b, x1);
  k_fps<<<B_, 256, 0, stream>>>(pos, psb);
  k_wsplit<<<64, 256, 0, stream>>>(bx1w, bx2w, w1hiT, w1loT, w2hiT, w2loT);
  k_knn<N_><<<B_*M_, 64, 0, stream>>>(psb, pos, nbrD);
  k_knn<M_><<<B_*M_, 64, 0, stream>>>(psb, psb, nbrS);
  k_downmax<<<B_*M_, 256, 0, stream>>>(x1, nbrD, dww, dwb, xA);
  k_kbR<<<NG_*NG_, 128, 0, stream>>>(grid, bR_rff, bR1w, bR1b, bR2w, bR2b, kbR);
  k_kbx<<<(B_*M_*K_*NG_)/128, 256, 0, stream>>>(psb, nbrS, grid, bx_rff,
      w1hiT, w1loT, w2hiT, w2loT, bx1b, bx2b, kbx);
  k_kR<<<NG_*NG_, 128, 0, stream>>>(kbR, i1kRw, i1kRb, kRb);
  k_inter<<<B_*M_, 256, 0, stream>>>(xA, nbrS, kbx, kRb, i1kxw, i1kxb, i1mw, i1mb, xB);
  k_kR<<<NG_*NG_, 128, 0, stream>>>(kbR, i2kRw, i2kRb, kRb);
  k_inter<<<B_*M_, 256, 0, stream>>>(xB, nbrS, kbx, kRb, i2kxw, i2kxb, i2mw, i2mb, xA);
  k_reduce<<<B_*64, 256, 0, stream>>>(xA, part);
  k_head<<<B_, 256, 0, stream>>>(part, p1w,p1b,p2w,p2b,p3w,p3b, out);
}

// Round 4
// 1351.279 us; speedup vs baseline: 1.9685x; 1.0265x over previous
//
#include <hip/hip_runtime.h>
#include <hip/hip_bf16.h>
#include <cfloat>

#define B_ 4
#define N_ 2048
#define NG_ 12
#define K_ 16
#define H_ 64
#define C_ 128
#define BD_ 64
#define M_ 512

typedef __attribute__((ext_vector_type(8))) short short8;
typedef __attribute__((ext_vector_type(4))) float floatx4;
typedef unsigned short ushort_t;
typedef unsigned int uint_t;

__device__ __forceinline__ float gelu_f(float x){
  // tanh-approx gelu via exp (matches jax.nn.gelu approximate=True to ~1e-6)
  float s = 0.7978845608028654f*(x + 0.044715f*x*x*x);
  float e = __expf(2.0f*s);
  float t = 1.0f - 2.0f/(e + 1.0f);
  return 0.5f*x*(1.0f + t);
}

__device__ __forceinline__ ushort_t bf16_rne(float x){
  uint_t u = __float_as_uint(x);
  uint_t r = (u + 0x7fffu + ((u >> 16) & 1u)) >> 16;
  return (ushort_t)r;
}

// ---------------- K1: lift + embed -> x1 [B,N,NG,H] ----------------
__global__ __launch_bounds__(256) void k_lift(
    const float* __restrict__ pos, const float* __restrict__ normal,
    const float* __restrict__ grid,
    const float* __restrict__ e1w, const float* __restrict__ e1b,
    const float* __restrict__ e2w, const float* __restrict__ e2b,
    float* __restrict__ x1){
  int tid = threadIdx.x;
  int q = tid>>6, lane = tid&63;
  int fid = blockIdx.x*4 + q;
  int g = fid % NG_;
  int n = (fid / NG_) % N_;
  int b = fid / (NG_*N_);
  const float* nm = normal + (size_t)(b*N_+n)*3;
  const float* pp = pos + (size_t)(b*N_+n)*3;
  const float* gg = grid + g*3;
  float f0 = nm[0]*gg[0] + nm[1]*gg[1] + nm[2]*gg[2];
  float t = e1b[lane] + f0*e1w[lane] + pp[0]*e1w[64+lane] + pp[1]*e1w[128+lane] + pp[2]*e1w[192+lane];
  __shared__ float ts[4][64];
  ts[q][lane] = gelu_f(t);
  __syncthreads();
  float acc = e2b[lane];
  #pragma unroll
  for (int i=0;i<64;++i) acc = fmaf(ts[q][i], e2w[i*64+lane], acc);
  x1[(size_t)fid*64 + lane] = acc;
}

// ---------------- K2: farthest point sampling -> ps [B,M,3] ----------------
// 4 waves; one barrier per iteration; redundant cross-wave winner compute.
__global__ __launch_bounds__(256) void k_fps(const float* __restrict__ pos, float* __restrict__ ps){
  int b = blockIdx.x, tid = threadIdx.x;
  __shared__ float posS[N_*3];
  __shared__ float2 wred[2][4];
  for (int i=tid;i<N_*3;i+=256) posS[i] = pos[(size_t)b*N_*3 + i];
  __syncthreads();
  float px[8],py[8],pz[8],d[8];
  #pragma unroll
  for (int j=0;j<8;++j){
    int n = tid + 256*j;
    px[j]=posS[n*3]; py[j]=posS[n*3+1]; pz[j]=posS[n*3+2];
    d[j]=1e10f;
  }
  int wave = tid>>6, lane = tid&63;
  int last = 0;
  for (int s=0;s<M_;++s){
    float lx=posS[last*3], ly=posS[last*3+1], lz=posS[last*3+2];
    if (tid==0){ float* o = ps + ((size_t)b*M_+s)*3; o[0]=lx;o[1]=ly;o[2]=lz; }
    float v=-1.0f; int vi=0x7fffffff;
    #pragma unroll
    for (int j=0;j<8;++j){
      float dx=__fsub_rn(px[j],lx), dy=__fsub_rn(py[j],ly), dz=__fsub_rn(pz[j],lz);
      float dist=__fadd_rn(__fadd_rn(__fmul_rn(dx,dx),__fmul_rn(dy,dy)),__fmul_rn(dz,dz));
      float dn = fminf(d[j],dist);
      d[j] = dn;
      if (dn>v){ v=dn; vi=tid+256*j; }
    }
    if (s==M_-1) break;
    #pragma unroll
    for (int off=32; off>0; off>>=1){
      float ov=__shfl_xor(v,off); int oi=__shfl_xor(vi,off);
      if (ov>v || (ov==v && oi<vi)){ v=ov; vi=oi; }
    }
    if (lane==0) wred[s&1][wave] = make_float2(v, __int_as_float(vi));
    __syncthreads();
    float2 r0 = wred[s&1][0], r1 = wred[s&1][1], r2 = wred[s&1][2], r3 = wred[s&1][3];
    float bv = r0.x; int bi = __float_as_int(r0.y);
    int i1 = __float_as_int(r1.y); if (r1.x>bv || (r1.x==bv && i1<bi)){ bv=r1.x; bi=i1; }
    int i2 = __float_as_int(r2.y); if (r2.x>bv || (r2.x==bv && i2<bi)){ bv=r2.x; bi=i2; }
    int i3 = __float_as_int(r3.y); if (r3.x>bv || (r3.x==bv && i3<bi)){ bv=r3.x; bi=i3; }
    last = bi;
  }
}

// ---------------- K3: exact KNN (k smallest d2, stable ties) ----------------
template<int NP>
__global__ __launch_bounds__(64) void k_knn(const float* __restrict__ qp, const float* __restrict__ pool,
                                            int* __restrict__ out){
  constexpr int R = NP/64;
  int lane = threadIdx.x;
  int qm = blockIdx.x;            // b*M + m
  int b = qm / M_;
  const float* q = qp + (size_t)qm*3;
  float qx=q[0], qy=q[1], qz=q[2];
  float d2[R];
  #pragma unroll
  for (int j=0;j<R;++j){
    int n = lane + 64*j;
    const float* p = pool + ((size_t)b*NP + n)*3;
    float dx=__fsub_rn(qx,p[0]), dy=__fsub_rn(qy,p[1]), dz=__fsub_rn(qz,p[2]);
    d2[j]=__fadd_rn(__fadd_rn(__fmul_rn(dx,dx),__fmul_rn(dy,dy)),__fmul_rn(dz,dz));
  }
  for (int r=0;r<K_;++r){
    float v=FLT_MAX; int vi=0x7fffffff;
    #pragma unroll
    for (int j=0;j<R;++j){ if (d2[j]<v){ v=d2[j]; vi=lane+64*j; } }
    #pragma unroll
    for (int off=32; off>0; off>>=1){
      float ov=__shfl_xor(v,off); int oi=__shfl_xor(vi,off);
      if (ov<v || (ov==v && oi<vi)){ v=ov; vi=oi; }
    }
    if (lane==0) out[(size_t)qm*K_ + r] = vi;
    #pragma unroll
    for (int j=0;j<R;++j){ if (vi == lane + 64*j) d2[j] = FLT_MAX; }
  }
}

// ---------------- K4: fused down-proj + relu + neighbor-max -> xA [B,M,NG,C] ----------------
__global__ __launch_bounds__(256) void k_downmax(
    const float* __restrict__ x1, const int* __restrict__ nbrD,
    const float* __restrict__ dw, const float* __restrict__ db,
    float* __restrict__ xA){
  int bm = blockIdx.x; int b = bm / M_;
  int tid = threadIdx.x;
  __shared__ int nb[K_];
  __shared__ float xs[K_][NG_*H_];     // 48 KB
  if (tid<K_) nb[tid] = nbrD[(size_t)bm*K_ + tid];
  __syncthreads();
  for (int idx=tid; idx<K_*NG_*H_/4; idx+=256){
    int k = idx / (NG_*H_/4), r = idx % (NG_*H_/4);
    ((float4*)&xs[k][0])[r] = ((const float4*)&x1[((size_t)(b*N_) + nb[k])*(NG_*H_)])[r];
  }
  __syncthreads();
  int c = tid & 127, gh = tid >> 7;
  float dbc = db[c];
  for (int gi=0; gi<6; ++gi){
    int g = gh*6 + gi;
    float acc[K_];
    #pragma unroll
    for (int k=0;k<K_;++k) acc[k]=dbc;
    for (int i4=0;i4<16;++i4){
      float w0 = dw[(i4*4+0)*C_ + c];
      float w1 = dw[(i4*4+1)*C_ + c];
      float w2 = dw[(i4*4+2)*C_ + c];
      float w3 = dw[(i4*4+3)*C_ + c];
      #pragma unroll
      for (int k=0;k<K_;++k){
        float4 xv = *(const float4*)&xs[k][g*H_ + i4*4];
        acc[k] = fmaf(xv.x,w0,fmaf(xv.y,w1,fmaf(xv.z,w2,fmaf(xv.w,w3,acc[k]))));
      }
    }
    float best = acc[0];
    #pragma unroll
    for (int k=1;k<K_;++k) best = fmaxf(best, acc[k]);
    xA[(size_t)bm*(NG_*C_) + g*C_ + c] = fmaxf(best, 0.0f);
  }
}

// ---------------- K5: kbR basis MLP [NG,NG,BD] ----------------
__global__ __launch_bounds__(128) void k_kbR(
    const float* __restrict__ grid, const float* __restrict__ rff,
    const float* __restrict__ w1, const float* __restrict__ b1,
    const float* __restrict__ w2, const float* __restrict__ b2,
    float* __restrict__ kbR){
  int gm = blockIdx.x / NG_, gn = blockIdx.x % NG_;
  int j = threadIdx.x;
  float z = grid[gm*3]*grid[gn*3] + grid[gm*3+1]*grid[gn*3+1] + grid[gm*3+2]*grid[gn*3+2];
  __shared__ float fs[128], hs[128];
  int jj = j & 63;
  float ang = 6.283185307179586f * (z * rff[jj]);
  fs[j] = (j<64) ? sinf(ang) : cosf(ang);
  __syncthreads();
  float acc = b1[j];
  for (int i=0;i<128;++i) acc = fmaf(fs[i], w1[i*128+j], acc);
  hs[j] = gelu_f(acc);
  __syncthreads();
  if (j < 64){
    float a2 = b2[j];
    for (int i=0;i<128;++i) a2 = fmaf(hs[i], w2[i*64+j], a2);
    kbR[(size_t)blockIdx.x*64 + j] = gelu_f(a2);
  }
}

// ---------------- K6: kR = kbR @ kR_w + b  [NG,NG,C] ----------------
__global__ __launch_bounds__(128) void k_kR(
    const float* __restrict__ kbR, const float* __restrict__ kRw, const float* __restrict__ kRb,
    float* __restrict__ kR){
  int pair = blockIdx.x; int c = threadIdx.x;
  __shared__ float kb[64];
  if (c<64) kb[c] = kbR[(size_t)pair*64 + c];
  __syncthreads();
  float acc = kRb[c];
  for (int d=0;d<64;++d) acc = fmaf(kb[d], kRw[d*128+c], acc);
  kR[(size_t)pair*128 + c] = acc;
}

// ---------------- K6b: split weights into transposed bf16 hi/lo ----------------
__global__ __launch_bounds__(256) void k_wsplit(
    const float* __restrict__ w1, const float* __restrict__ w2,
    ushort_t* __restrict__ w1hiT, ushort_t* __restrict__ w1loT,
    ushort_t* __restrict__ w2hiT, ushort_t* __restrict__ w2loT){
  int tid = blockIdx.x*256 + threadIdx.x;
  if (tid < 16384){
    int j = tid >> 7, k = tid & 127;
    float x = w1[k*128 + j];
    ushort_t hi = bf16_rne(x);
    float hif = __uint_as_float(((uint_t)hi)<<16);
    ushort_t lo = bf16_rne(x - hif);
    w1hiT[tid] = hi; w1loT[tid] = lo;
  }
  if (tid < 8192){
    int c = tid >> 7, j = tid & 127;
    float x = w2[j*64 + c];
    ushort_t hi = bf16_rne(x);
    float hif = __uint_as_float(((uint_t)hi)<<16);
    ushort_t lo = bf16_rne(x - hif);
    w2hiT[tid] = hi; w2loT[tid] = lo;
  }
}

// ---------------- K7: kbx basis MLP via MFMA bf16 x3 (hi/lo split) ----------------
// block = 256 thr = 4 waves; each wave owns 32 fibers; block = 128 fibers.
__global__ __launch_bounds__(256) void k_kbx(
    const float* __restrict__ ps, const int* __restrict__ nbr,
    const float* __restrict__ grid, const float* __restrict__ rff,
    const ushort_t* __restrict__ w1hiT, const ushort_t* __restrict__ w1loT,
    const ushort_t* __restrict__ w2hiT, const ushort_t* __restrict__ w2loT,
    const float* __restrict__ b1, const float* __restrict__ b2,
    float* __restrict__ kbx){
  __shared__ float z0s[128], z1s[128], rws[128];
  __shared__ float bounce[4][32*34];
  int tid = threadIdx.x;
  if (tid < 128){
    rws[tid] = rff[tid];
    int fid = blockIdx.x*128 + tid;
    int g = fid % NG_;
    int k = (fid/NG_) % K_;
    int bm = fid / (NG_*K_);
    int b = bm / M_;
    int nb = nbr[(size_t)bm*K_ + k];
    const float* pm = ps + (size_t)bm*3;
    const float* pn = ps + ((size_t)(b*M_) + nb)*3;
    float rx = pn[0]-pm[0], ry = pn[1]-pm[1], rz3 = pn[2]-pm[2];
    const float* gg = grid + g*3;
    float rz = rx*gg[0] + ry*gg[1] + rz3*gg[2];
    float vx = rx - rz*gg[0], vy = ry - rz*gg[1], vz = rz3 - rz*gg[2];
    float rxy = sqrtf(vx*vx + vy*vy + vz*vz + 1e-12f);
    z0s[tid]=rxy; z1s[tid]=rz;
  }
  __syncthreads();
  int wid = tid>>6, lane = tid&63;
  int ln = lane & 15, g = lane >> 4;

  // ---- A fragments (RFF features), computed fully in registers ----
  short8 ahi[2][4], alo[2][4];
  #pragma unroll
  for (int rt=0; rt<2; ++rt){
    float z0 = z0s[wid*32 + rt*16 + ln];
    float z1 = z1s[wid*32 + rt*16 + ln];
    #pragma unroll
    for (int ks=0; ks<4; ++ks){
      #pragma unroll
      for (int e=0; e<8; ++e){
        int kd = ks*32 + g*8 + e;
        int kk = kd & 63;
        float t = z0*rws[kk] + z1*rws[64+kk];
        t = t - floorf(t);
        float v = (ks < 2) ? __builtin_amdgcn_sinf(t) : __builtin_amdgcn_cosf(t);
        ushort_t hi = bf16_rne(v);
        float hif = __uint_as_float(((uint_t)hi)<<16);
        ushort_t lo = bf16_rne(v - hif);
        ahi[rt][ks][e] = (short)hi;
        alo[rt][ks][e] = (short)lo;
      }
    }
  }

  floatx4 acc2[2][4];
  #pragma unroll
  for (int rt=0; rt<2; ++rt)
    #pragma unroll
    for (int ct=0; ct<4; ++ct)
      acc2[rt][ct] = (floatx4){0.f,0.f,0.f,0.f};

  float* bw = &bounce[wid][0];

  #pragma unroll
  for (int jp=0; jp<4; ++jp){
    // ---- GEMM1 partial: 32 output cols (jp*32 .. +32) ----
    floatx4 acc1[2][2];
    #pragma unroll
    for (int rt=0; rt<2; ++rt)
      #pragma unroll
      for (int jt=0; jt<2; ++jt)
        acc1[rt][jt] = (floatx4){0.f,0.f,0.f,0.f};
    #pragma unroll
    for (int ks=0; ks<4; ++ks){
      #pragma unroll
      for (int jt=0; jt<2; ++jt){
        int j = jp*32 + jt*16 + ln;
        short8 bhi = *(const short8*)&w1hiT[(size_t)j*128 + ks*32 + g*8];
        short8 blo = *(const short8*)&w1loT[(size_t)j*128 + ks*32 + g*8];
        #pragma unroll
        for (int rt=0; rt<2; ++rt){
          acc1[rt][jt] = __builtin_amdgcn_mfma_f32_16x16x32_bf16(ahi[rt][ks], bhi, acc1[rt][jt], 0,0,0);
          acc1[rt][jt] = __builtin_amdgcn_mfma_f32_16x16x32_bf16(alo[rt][ks], bhi, acc1[rt][jt], 0,0,0);
          acc1[rt][jt] = __builtin_amdgcn_mfma_f32_16x16x32_bf16(ahi[rt][ks], blo, acc1[rt][jt], 0,0,0);
        }
      }
    }
    // ---- gelu + bounce to LDS (wave-private, no barrier needed) ----
    #pragma unroll
    for (int jt=0; jt<2; ++jt){
      float bb = b1[jp*32 + jt*16 + ln];
      #pragma unroll
      for (int rt=0; rt<2; ++rt)
        #pragma unroll
        for (int i=0; i<4; ++i)
          bw[(rt*16 + g*4 + i)*34 + jt*16 + ln] = gelu_f(bb + acc1[rt][jt][i]);
    }
    // ---- GEMM2 partial: contract these 32 j's ----
    #pragma unroll
    for (int rt=0; rt<2; ++rt){
      int base = (rt*16 + ln)*34 + g*8;
      float2 p0 = *(float2*)&bw[base+0];
      float2 p1 = *(float2*)&bw[base+2];
      float2 p2 = *(float2*)&bw[base+4];
      float2 p3 = *(float2*)&bw[base+6];
      float hv[8] = {p0.x,p0.y,p1.x,p1.y,p2.x,p2.y,p3.x,p3.y};
      short8 a2h, a2l;
      #pragma unroll
      for (int e=0; e<8; ++e){
        ushort_t hi = bf16_rne(hv[e]);
        float hif = __uint_as_float(((uint_t)hi)<<16);
        ushort_t lo = bf16_rne(hv[e] - hif);
        a2h[e] = (short)hi;
        a2l[e] = (short)lo;
      }
      #pragma unroll
      for (int ct=0; ct<4; ++ct){
        short8 b2h = *(const short8*)&w2hiT[(size_t)(ct*16+ln)*128 + jp*32 + g*8];
        short8 b2l = *(const short8*)&w2loT[(size_t)(ct*16+ln)*128 + jp*32 + g*8];
        acc2[rt][ct] = __builtin_amdgcn_mfma_f32_16x16x32_bf16(a2h, b2h, acc2[rt][ct], 0,0,0);
        acc2[rt][ct] = __builtin_amdgcn_mfma_f32_16x16x32_bf16(a2l, b2h, acc2[rt][ct], 0,0,0);
        acc2[rt][ct] = __builtin_amdgcn_mfma_f32_16x16x32_bf16(a2h, b2l, acc2[rt][ct], 0,0,0);
      }
    }
  }
  // ---- epilogue: gelu + store ----
  #pragma unroll
  for (int ct=0; ct<4; ++ct){
    float bb = b2[ct*16 + ln];
    #pragma unroll
    for (int rt=0; rt<2; ++rt)
      #pragma unroll
      for (int i=0; i<4; ++i){
        int row = wid*32 + rt*16 + g*4 + i;
        size_t fiber = (size_t)blockIdx.x*128 + row;
        kbx[fiber*64 + ct*16 + ln] = gelu_f(bb + acc2[rt][ct][i]);
      }
  }
}

// ---------------- K8: interaction layer ----------------
__global__ __launch_bounds__(256) void k_inter(
    const float* __restrict__ xin, const int* __restrict__ nbr,
    const float* __restrict__ kbx, const float* __restrict__ kR,
    const float* __restrict__ kxw, const float* __restrict__ kxb,
    const float* __restrict__ mw, const float* __restrict__ mb,
    float* __restrict__ xout){
  int bm = blockIdx.x; int b = bm / M_;
  int tid = threadIdx.x;
  int c = tid & 127, gh = tid >> 7;
  __shared__ float kbs[NG_*BD_];    // 3 KB
  __shared__ float xns[NG_*C_];     // 6 KB
  __shared__ float aggS[NG_][C_];   // 6 KB
  __shared__ float yS[NG_][C_];     // 6 KB
  // hoist kxw column into registers (reused across all 16 k iterations)
  float wreg[64];
  #pragma unroll
  for (int d=0; d<64; ++d) wreg[d] = kxw[d*C_ + c];
  float accg[6] = {0,0,0,0,0,0};
  float kxbc = kxb[c];
  for (int k=0;k<K_;++k){
    int nb = nbr[(size_t)bm*K_ + k];
    __syncthreads();
    {
      const float4* src = (const float4*)&kbx[((size_t)bm*K_ + k)*(NG_*BD_)];
      for (int idx=tid; idx<NG_*BD_/4; idx+=256) ((float4*)kbs)[idx] = src[idx];
      const float4* src2 = (const float4*)&xin[((size_t)(b*M_) + nb)*(NG_*C_)];
      for (int idx=tid; idx<NG_*C_/4; idx+=256) ((float4*)xns)[idx] = src2[idx];
    }
    __syncthreads();
    float t6[6] = {0,0,0,0,0,0};
    #pragma unroll
    for (int d4=0; d4<16; ++d4){
      #pragma unroll
      for (int gi=0; gi<6; ++gi){
        int g = gh*6+gi;
        float4 kv = *(const float4*)&kbs[g*BD_ + d4*4];
        t6[gi] = fmaf(kv.x,wreg[d4*4+0],fmaf(kv.y,wreg[d4*4+1],fmaf(kv.z,wreg[d4*4+2],fmaf(kv.w,wreg[d4*4+3],t6[gi]))));
      }
    }
    #pragma unroll
    for (int gi=0; gi<6; ++gi){
      int g = gh*6+gi;
      accg[gi] = fmaf(t6[gi]+kxbc, xns[g*C_+c], accg[gi]);
    }
  }
  __syncthreads();
  #pragma unroll
  for (int gi=0; gi<6; ++gi)
    aggS[gh*6+gi][c] = accg[gi] * (1.0f/16.0f);
  __syncthreads();
  #pragma unroll
  for (int gi=0; gi<6; ++gi){
    int g = gh*6+gi;
    float yv = 0.f;
    #pragma unroll
    for (int n=0;n<NG_;++n) yv = fmaf(aggS[n][c], kR[((size_t)g*NG_+n)*C_ + c], yv);
    yS[g][c] = yv * (1.0f/12.0f);
  }
  __syncthreads();
  float m6[6] = {0,0,0,0,0,0};
  for (int i4=0;i4<32;++i4){
    float w0 = mw[(i4*4+0)*C_+c], w1 = mw[(i4*4+1)*C_+c],
          w2 = mw[(i4*4+2)*C_+c], w3 = mw[(i4*4+3)*C_+c];
    #pragma unroll
    for (int gi=0;gi<6;++gi){
      int g = gh*6+gi;
      float4 yv = *(const float4*)&yS[g][i4*4];
      m6[gi] = fmaf(yv.x,w0,fmaf(yv.y,w1,fmaf(yv.z,w2,fmaf(yv.w,w3,m6[gi]))));
    }
  }
  float mbc = mb[c];
  #pragma unroll
  for (int gi=0;gi<6;++gi){
    int g = gh*6+gi;
    size_t off = (size_t)bm*(NG_*C_) + g*C_ + c;
    xout[off] = xin[off] + gelu_f(m6[gi] + mbc);
  }
}

// ---------------- K9a: parallel partial reduction ----------------
__global__ __launch_bounds__(256) void k_reduce(
    const float* __restrict__ x, float* __restrict__ part){
  int blk = blockIdx.x;
  int b = blk >> 6, ch = blk & 63;
  int tid = threadIdx.x;
  int c = tid & 127, half = tid >> 7;
  const float* xb = x + (size_t)b*(M_*NG_)*C_;
  int r0 = ch*96;
  float acc = 0.f;
  for (int r = r0 + half; r < r0 + 96; r += 2)
    acc += xb[(size_t)r*C_ + c];
  __shared__ float red[256];
  red[tid] = acc;
  __syncthreads();
  if (half == 0)
    part[(size_t)blk*C_ + c] = red[c] + red[128 + c];
}

// ---------------- K9b: final reduce + MLP head ----------------
__global__ __launch_bounds__(256) void k_head(
    const float* __restrict__ part,
    const float* __restrict__ p1w, const float* __restrict__ p1b,
    const float* __restrict__ p2w, const float* __restrict__ p2b,
    const float* __restrict__ p3w, const float* __restrict__ p3b,
    float* __restrict__ out){
  int b = blockIdx.x, tid = threadIdx.x;
  __shared__ float gs[128];
  if (tid < 128){
    float a = 0.f;
    const float* pb = part + (size_t)b*64*C_;
    for (int ch = 0; ch < 64; ++ch) a += pb[(size_t)ch*C_ + tid];
    gs[tid] = a * (1.0f/(M_*NG_));
  }
  __syncthreads();
  __shared__ float h1[256];
  {
    float a = p1b[tid];
    for (int i=0;i<128;++i) a = fmaf(gs[i], p1w[i*256+tid], a);
    h1[tid] = gelu_f(a);
  }
  __syncthreads();
  __shared__ float h2[64];
  if (tid<64){
    float a = p2b[tid];
    for (int i=0;i<256;++i) a = fmaf(h1[i], p2w[i*64+tid], a);
    h2[tid] = gelu_f(a);
  }
  __syncthreads();
  if (tid==0){
    float a = p3b[0];
    for (int i=0;i<64;++i) a = fmaf(h2[i], p3w[i], a);
    out[b] = a;
  }
}

extern "C" void kernel_launch(void* const* d_in, const int* in_sizes, int n_in,
                              void* d_out, int out_size, void* d_ws, size_t ws_size,
                              hipStream_t stream){
  const float* pos    = (const float*)d_in[0];
  const float* normal = (const float*)d_in[1];
  const float* grid   = (const float*)d_in[2];
  const float* e1w = (const float*)d_in[3];  const float* e1b = (const float*)d_in[4];
  const float* e2w = (const float*)d_in[5];  const float* e2b = (const float*)d_in[6];
  const float* dww = (const float*)d_in[7];  const float* dwb = (const float*)d_in[8];
  const float* bx_rff = (const float*)d_in[9];
  const float* bx1w = (const float*)d_in[10]; const float* bx1b = (const float*)d_in[11];
  const float* bx2w = (const float*)d_in[12]; const float* bx2b = (const float*)d_in[13];
  const float* bR_rff = (const float*)d_in[14];
  const float* bR1w = (const float*)d_in[15]; const float* bR1b = (const float*)d_in[16];
  const float* bR2w = (const float*)d_in[17]; const float* bR2b = (const float*)d_in[18];
  const float* i1kxw = (const float*)d_in[19]; const float* i1kxb = (const float*)d_in[20];
  const float* i1kRw = (const float*)d_in[21]; const float* i1kRb = (const float*)d_in[22];
  const float* i1mw  = (const float*)d_in[23]; const float* i1mb  = (const float*)d_in[24];
  const float* i2kxw = (const float*)d_in[25]; const float* i2kxb = (const float*)d_in[26];
  const float* i2kRw = (const float*)d_in[27]; const float* i2kRb = (const float*)d_in[28];
  const float* i2mw  = (const float*)d_in[29]; const float* i2mb  = (const float*)d_in[30];
  const float* p1w = (const float*)d_in[31]; const float* p1b = (const float*)d_in[32];
  const float* p2w = (const float*)d_in[33]; const float* p2b = (const float*)d_in[34];
  const float* p3w = (const float*)d_in[35]; const float* p3b = (const float*)d_in[36];
  float* out = (float*)d_out;

  float* ws = (float*)d_ws;
  size_t o = 0;
  float* x1  = ws + o; o += (size_t)B_*N_*NG_*H_;       // 6,291,456
  float* psb = ws + o; o += (size_t)B_*M_*3;            // 6,144
  float* xA  = ws + o; o += (size_t)B_*M_*NG_*C_;       // 3,145,728
  float* xB  = ws + o; o += (size_t)B_*M_*NG_*C_;       // 3,145,728
  float* kbx = ws + o; o += (size_t)B_*M_*K_*NG_*BD_;   // 25,165,824
  float* kbR = ws + o; o += (size_t)NG_*NG_*BD_;        // 9,216
  float* kRb = ws + o; o += (size_t)NG_*NG_*C_;         // 18,432
  float* part = ws + o; o += (size_t)B_*64*C_;          // 32,768
  int* nbrD  = (int*)(ws + o); o += (size_t)B_*M_*K_;   // 32,768
  int* nbrS  = (int*)(ws + o); o += (size_t)B_*M_*K_;   // 32,768
  ushort_t* w1hiT = (ushort_t*)(ws + o); o += 8192;     // 16384 ushort
  ushort_t* w1loT = (ushort_t*)(ws + o); o += 8192;
  ushort_t* w2hiT = (ushort_t*)(ws + o); o += 4096;     // 8192 ushort
  ushort_t* w2loT = (ushort_t*)(ws + o); o += 4096;

  k_lift<<<B_*N_*NG_/4, 256, 0, stream>>>(pos, normal, grid, e1w,e1b,e2w,e2b, x1);
  k_fps<<<B_, 256, 0, stream>>>(pos, psb);
  k_wsplit<<<64, 256, 0, stream>>>(bx1w, bx2w, w1hiT, w1loT, w2hiT, w2loT);
  k_knn<N_><<<B_*M_, 64, 0, stream>>>(psb, pos, nbrD);
  k_knn<M_><<<B_*M_, 64, 0, stream>>>(psb, psb, nbrS);
  k_downmax<<<B_*M_, 256, 0, stream>>>(x1, nbrD, dww, dwb, xA);
  k_kbR<<<NG_*NG_, 128, 0, stream>>>(grid, bR_rff, bR1w, bR1b, bR2w, bR2b, kbR);
  k_kbx<<<(B_*M_*K_*NG_)/128, 256, 0, stream>>>(psb, nbrS, grid, bx_rff,
      w1hiT, w1loT, w2hiT, w2loT, bx1b, bx2b, kbx);
  k_kR<<<NG_*NG_, 128, 0, stream>>>(kbR, i1kRw, i1kRb, kRb);
  k_inter<<<B_*M_, 256, 0, stream>>>(xA, nbrS, kbx, kRb, i1kxw, i1kxb, i1mw, i1mb, xB);
  k_kR<<<NG_*NG_, 128, 0, stream>>>(kbR, i2kRw, i2kRb, kRb);
  k_inter<<<B_*M_, 256, 0, stream>>>(xB, nbrS, kbx, kRb, i2kxw, i2kxb, i2mw, i2mb, xA);
  k_reduce<<<B_*64, 256, 0, stream>>>(xA, part);
  k_head<<<B_, 256, 0, stream>>>(part, p1w,p1b,p2w,p2b,p3w,p3b, out);
}